// Round 12
// baseline (339.430 us; speedup 1.0000x reference)
//
#include <hip/hip_runtime.h>

// ---------------------------------------------------------------------------
// SimVP Decoder, round 12: all intermediates are padded NHWC bf16, pre-norm.
//   conv writes pre-norm bf16 NHWC directly (stats fused, f32 accumulators);
//   act pass becomes IN-PLACE elementwise GN+SiLU (+enc1) on the same buffer
//   (no transpose, half the traffic); readout consumes NHWC rows directly.
// Conv compute core identical to R11 (passed): single-staged row strip,
// 36 named weight v8s resident (waves_per_eu), barrier-free row-pair loop,
// slot-spread stats atomics (R8).
// Pipeline:
//   pad(hid)->hidP ; conv0+PS->Abf ; actn1(Abf) ; conv1->Bbf ; actn2(Bbf)
//   conv2+PS->Cbf ; actn3(Cbf,+enc1) ; conv3->Dbf ; readout(Dbf)->Y
//   feamap -> argx ; nz ; final
// ---------------------------------------------------------------------------

#define DEVFN static __device__ __forceinline__

typedef short v8s __attribute__((ext_vector_type(8)));
typedef float v4f __attribute__((ext_vector_type(4)));

DEVFN float silu_f(float t) { return t / (1.f + __expf(-t)); }

DEVFN ushort f2bf(float x) {
  union { float f; unsigned u; } t; t.f = x;
  unsigned r = t.u + 0x7FFFu + ((t.u >> 16) & 1u);
  return (ushort)(r >> 16);
}

DEVFN float bf2f(unsigned u) {
  union { unsigned i; float f; } t; t.i = u << 16; return t.f;
}

__global__ void zero_k(float* __restrict__ p, int n) {
  int i = blockIdx.x * 256 + threadIdx.x;
  if (i < n) p[i] = 0.f;
}

// ---- weight repack: [OC][64][3][3] f32 -> bf16 [kc=tap*8+ic/8][OC][8] -----
template<int OC>
__global__ void repackw_k(const float* __restrict__ src, ushort* __restrict__ dst) {
  int i = blockIdx.x * 256 + threadIdx.x;
  if (i >= OC * 576) return;
  int oc = i / 576, r = i - oc * 576;      // r = ic*9 + tap
  int ic = r / 9, tap = r - ic * 9;
  int kc = tap * 8 + (ic >> 3), j = ic & 7;
  dst[((size_t)kc * OC + oc) * 8 + j] = f2bf(src[i]);
}

// ---- zero the 1-px border of a padded NHWC bf16 buffer --------------------
template<int HP, int WP>
__global__ void border_k(ushort* __restrict__ outP) {
  int idx = blockIdx.x * 256 + threadIdx.x;
  if (idx >= 16 * HP * WP) return;
  int p = idx % (HP * WP);
  int y = p / WP, x = p - y * WP;
  if (y == 0 || y == HP - 1 || x == 0 || x == WP - 1) {
    uint4 z = {0u, 0u, 0u, 0u};
    uint4* dst = (uint4*)(outP + (size_t)idx * 64);
    #pragma unroll
    for (int k = 0; k < 8; ++k) dst[k] = z;
  }
}

// ---- slot-summed GN stats -> (mean, rstd) ---------------------------------
DEVFN void gn_stats(const float* __restrict__ st, int bg, float N,
                    float& mean, float& rstd) {
  float s = 0.f, q = 0.f;
  #pragma unroll
  for (int sl = 0; sl < 8; ++sl) {
    s += st[sl * 64 + bg * 2 + 0];
    q += st[sl * 64 + bg * 2 + 1];
  }
  float m = s / N;
  mean = m;
  rstd = rsqrtf(q / N - m * m + 1e-5f);
}

// ---- pad/transpose: NCHW f32 -> padded NHWC bf16 (raw copy, for hid) ------
template<int HW_TOT, int WOUT>
__global__ __launch_bounds__(256)
void pad_k(const float* __restrict__ in, ushort* __restrict__ outP)
{
  constexpr int HOUT = HW_TOT / WOUT;
  constexpr int WP = WOUT + 2, HP = HOUT + 2;
  __shared__ uint4 sT[256 * 8];
  const int tid = threadIdx.x;
  constexpr int NBLK = (HW_TOT + 255) / 256;
  const int b  = blockIdx.x / NBLK;
  const int p0 = (blockIdx.x - b * NBLK) * 256;
  const int px = p0 + tid;

  if (px < HW_TOT) {
    const float* ip = in + (size_t)b * 64 * HW_TOT + px;
    #pragma unroll 2
    for (int cc = 0; cc < 8; ++cc) {
      unsigned w[4];
      #pragma unroll
      for (int jp = 0; jp < 4; ++jp) {
        float v0 = ip[(size_t)(cc * 8 + jp * 2) * HW_TOT];
        float v1 = ip[(size_t)(cc * 8 + jp * 2 + 1) * HW_TOT];
        w[jp] = (unsigned)f2bf(v0) | ((unsigned)f2bf(v1) << 16);
      }
      uint4 pk = {w[0], w[1], w[2], w[3]};
      sT[tid * 8 + (cc ^ (tid & 7))] = pk;
    }
  }
  __syncthreads();
  const int o = tid & 7, pr = tid >> 3;
  #pragma unroll
  for (int i = 0; i < 8; ++i) {
    int p = i * 32 + pr;
    int gpx = p0 + p;
    if (gpx < HW_TOT) {
      int y = gpx / WOUT, x = gpx - y * WOUT;
      uint4 val = sT[p * 8 + (o ^ (p & 7))];
      *(uint4*)(outP + (((size_t)(b * HP) + y + 1) * WP + (x + 1)) * 64 + o * 8) = val;
    }
  }
}

// ---- in-place GN+SiLU (+enc1) on padded NHWC bf16 interior ----------------
template<int HOUT, int WOUT, bool ADD>
__global__ __launch_bounds__(256)
void actn_k(ushort* __restrict__ buf, const float* __restrict__ st,
            const float* __restrict__ gw, const float* __restrict__ gb,
            const float* __restrict__ addsrc)
{
  constexpr int HW = HOUT * WOUT;
  constexpr int WP = WOUT + 2, HP = HOUT + 2;
  int idx = blockIdx.x * 256 + threadIdx.x;
  if (idx >= 16 * HW) return;
  int b = idx / HW, pix = idx - b * HW;
  int y = pix / WOUT, x = pix - y * WOUT;

  const float N = 32.f * HW;
  float mean[2], rstd[2];
  #pragma unroll
  for (int g = 0; g < 2; ++g) gn_stats(st, b * 2 + g, N, mean[g], rstd[g]);

  uint4* pv = (uint4*)(buf + (((size_t)(b * HP) + y + 1) * WP + (x + 1)) * 64);
  const float* ap = ADD ? (addsrc + (size_t)b * 64 * HW + pix) : nullptr;

  #pragma unroll
  for (int cc = 0; cc < 8; ++cc) {
    uint4 v = pv[cc];
    unsigned r[4];
    #pragma unroll
    for (int k = 0; k < 4; ++k) {
      unsigned w = (k == 0) ? v.x : (k == 1) ? v.y : (k == 2) ? v.z : v.w;
      const int c0 = cc * 8 + k * 2;
      const int g = c0 >> 5;
      float f0 = bf2f(w & 0xffffu), f1 = bf2f(w >> 16);
      float r0 = silu_f((f0 - mean[g]) * rstd[g] * gw[c0] + gb[c0]);
      float r1 = silu_f((f1 - mean[g]) * rstd[g] * gw[c0 + 1] + gb[c0 + 1]);
      if (ADD) {
        r0 += ap[(size_t)c0 * HW];
        r1 += ap[(size_t)(c0 + 1) * HW];
      }
      r[k] = (unsigned)f2bf(r0) | ((unsigned)f2bf(r1) << 16);
    }
    uint4 pk = {r[0], r[1], r[2], r[3]};
    pv[cc] = pk;
  }
}

// ---- MFMA implicit-GEMM 3x3 conv, single-staged row strip -----------------
// In: padded NHWC bf16. Out: padded NHWC bf16, PRE-NORM (stats fused).
// Block: RPB rows x WT px x 64 oc; wave = 1 row x 32 oc; 36 named weight
// v8s resident (waves_per_eu caps occupancy, not registers).

#define FE18(M) M(0) M(1) M(2) M(3) M(4) M(5) M(6) M(7) M(8) M(9) M(10) \
                M(11) M(12) M(13) M(14) M(15) M(16) M(17)

#define WDL(t) \
  v8s Wa##t = ((const v8s*)wrep)[(size_t)((t) * 4 + sub) * OCT + ocbase + lx]; \
  v8s Wb##t = ((const v8s*)wrep)[(size_t)((t) * 4 + sub) * OCT + ocbase + 16 + lx];

#define KST(t) { \
    const int col_ = xb + lx + (((t) >> 1) % 3); \
    v8s b_ = __builtin_bit_cast(v8s, sQ[((rbase + wrow + (t) / 6) * LWS + col_) * 8 + \
                                        (((((t) & 1) * 4 + sub)) ^ (col_ & 7))]); \
    a0 = __builtin_amdgcn_mfma_f32_16x16x32_bf16(Wa##t, b_, a0, 0, 0, 0); \
    a1 = __builtin_amdgcn_mfma_f32_16x16x32_bf16(Wb##t, b_, a1, 0, 0, 0); }

template<int HIN, int WIN, int WT, int NG, int RPB, int OCT, bool PSF,
         int WEU_MIN, int WEU_MAX>
__global__
__attribute__((amdgpu_flat_work_group_size(256, 256),
               amdgpu_waves_per_eu(WEU_MIN, WEU_MAX)))
void convm_k(const uint4* __restrict__ inP, const ushort* __restrict__ wrep,
             const float* __restrict__ bias, ushort* __restrict__ outP,
             float* __restrict__ stp)
{
  constexpr int HP = HIN + 2, WP = WIN + 2;
  constexpr int HPo = PSF ? (2 * HIN + 2) : (HIN + 2);
  constexpr int WPo = PSF ? (2 * WIN + 2) : (WIN + 2);
  constexpr int LH = RPB + 2, LW = WT + 2;
  constexpr int NOCB = OCT / 64;
  constexpr int LRD = (NG * 16 + 2 > LW) ? (NG * 16 + 2) : LW;
  constexpr int LWS = (LRD + 7) & ~7;      // multiple of 8: (pix&7)==(col&7)
  constexpr int NCHUNK = LH * LWS * 8;
  static_assert(NCHUNK % 256 == 0, "staging must tile evenly");
  constexpr int STK = NCHUNK / 256;
  __shared__ uint4 sQ[NCHUNK];
  __shared__ float red[4][2];

  const int tid  = threadIdx.x;
  const int lane = tid & 63;
  const int wave = tid >> 6;
  const int sub  = lane >> 4;
  const int lx   = lane & 15;
  const int wrow = wave >> 1;              // row within pair
  const int b    = blockIdx.y / NOCB;
  const int ocb  = blockIdx.y - b * NOCB;
  constexpr int NTX = WIN / WT;
  const int tx    = blockIdx.x % NTX;
  const int ych   = blockIdx.x / NTX;
  const int x0    = tx * WT;
  const int ybase = ych * RPB;
  const int ocbase = ocb * 64 + (wave & 1) * 32;

  FE18(WDL)

  const v4f bi0 = *(const v4f*)&bias[ocbase + sub * 4];
  const v4f bi1 = *(const v4f*)&bias[ocbase + 16 + sub * 4];

  // stage the whole (RPB+2)-row strip once (batched loads, one wait)
  const uint4* gbase = inP + ((size_t)(b * HP + ybase) * WP + x0) * 8;
  uint4 stg[STK];
  #pragma unroll
  for (int k = 0; k < STK; ++k) {
    int q = tid + k * 256;
    int p = q >> 3, cc = q & 7;
    int r = p / LWS, cx = p - r * LWS;
    stg[k] = gbase[((size_t)r * WP + cx) * 8 + cc];
  }
  #pragma unroll
  for (int k = 0; k < STK; ++k) {
    int q = tid + k * 256;
    int p = q >> 3, cc = q & 7;
    int cx = p - (p / LWS) * LWS;
    sQ[p * 8 + (cc ^ (cx & 7))] = stg[k];
  }
  __syncthreads();

  float sA = 0.f, qA = 0.f;

  for (int it = 0; it < RPB / 2; ++it) {
    const int rbase = it * 2;
    const int y = ybase + rbase + wrow;
    for (int xg = 0; xg < NG; ++xg) {
      const int xb = xg * 16;
      v4f a0 = bi0, a1 = bi1;
      FE18(KST)
      const int x = x0 + xb + lx;
      if ((NG * 16 == WT) || (x < WIN)) {
        if (!PSF) {
          // NHWC row: channel offset = (wave&1)*32 + s*16 + sub*4
          const size_t pbase =
            (((size_t)(b * HPo) + y + 1) * WPo + (x + 1)) * 64 + (wave & 1) * 32;
          #pragma unroll
          for (int s = 0; s < 2; ++s) {
            const v4f a = s ? a1 : a0;
            uint2 pk;
            pk.x = (unsigned)f2bf(a[0]) | ((unsigned)f2bf(a[1]) << 16);
            pk.y = (unsigned)f2bf(a[2]) | ((unsigned)f2bf(a[3]) << 16);
            *(uint2*)(outP + pbase + s * 16 + sub * 4) = pk;
            #pragma unroll
            for (int j = 0; j < 4; ++j) { sA += a[j]; qA += a[j] * a[j]; }
          }
        } else {
          #pragma unroll
          for (int s = 0; s < 2; ++s) {
            const v4f a = s ? a1 : a0;
            #pragma unroll
            for (int j = 0; j < 4; ++j) {
              int oc = ocbase + s * 16 + sub * 4 + j;
              int c = oc >> 2, rr = (oc >> 1) & 1, ss = oc & 1;
              outP[(((size_t)(b * HPo) + 2 * y + rr + 1) * WPo
                    + (2 * x + ss + 1)) * 64 + c] = f2bf(a[j]);
              sA += a[j]; qA += a[j] * a[j];
            }
          }
        }
      }
    }
  }

  // GroupNorm stats (f32 accumulators, exact)
  #pragma unroll
  for (int o = 32; o >= 1; o >>= 1) {
    sA += __shfl_down(sA, o);
    qA += __shfl_down(qA, o);
  }
  if (lane == 0) { red[wave][0] = sA; red[wave][1] = qA; }
  __syncthreads();
  if (tid == 0) {
    float* basep = stp + ((blockIdx.x ^ blockIdx.y) & 7) * 64;
    if (PSF) {
      int g = ocb >> 1;
      atomicAdd(&basep[(b * 2 + g) * 2 + 0],
                red[0][0] + red[1][0] + red[2][0] + red[3][0]);
      atomicAdd(&basep[(b * 2 + g) * 2 + 1],
                red[0][1] + red[1][1] + red[2][1] + red[3][1]);
    } else {
      atomicAdd(&basep[(b * 2 + 0) * 2 + 0], red[0][0] + red[2][0]);
      atomicAdd(&basep[(b * 2 + 0) * 2 + 1], red[0][1] + red[2][1]);
      atomicAdd(&basep[(b * 2 + 1) * 2 + 0], red[1][0] + red[3][0]);
      atomicAdd(&basep[(b * 2 + 1) * 2 + 1], red[1][1] + red[3][1]);
    }
  }
}

// ---- readout from padded NHWC bf16 pre-norm D -----------------------------
__global__ __launch_bounds__(256)
void readout_k(const ushort* __restrict__ Dp, const float* __restrict__ st,
               const float* __restrict__ gw, const float* __restrict__ gb,
               const float* __restrict__ rw, const float* __restrict__ rb,
               float* __restrict__ Y)
{
  int idx = blockIdx.x * 256 + threadIdx.x;
  if (idx >= 16 * 25600) return;
  int b = idx / 25600, pix = idx - b * 25600;
  int y = pix / 160, x = pix - y * 160;
  const float N = 32.f * 25600.f;
  float mean[2], rstd[2];
  #pragma unroll
  for (int g = 0; g < 2; ++g) gn_stats(st, b * 2 + g, N, mean[g], rstd[g]);

  const uint4* p = (const uint4*)(Dp + (((size_t)(b * 162) + y + 1) * 162
                                        + (x + 1)) * 64);
  float a0 = rb[0], a1 = rb[1], a2 = rb[2];
  #pragma unroll
  for (int cc = 0; cc < 8; ++cc) {
    uint4 v = p[cc];
    #pragma unroll
    for (int k = 0; k < 4; ++k) {
      unsigned w = (k == 0) ? v.x : (k == 1) ? v.y : (k == 2) ? v.z : v.w;
      const int c0 = cc * 8 + k * 2;
      const int g = c0 >> 5;
      float f0 = bf2f(w & 0xffffu), f1 = bf2f(w >> 16);
      float v0 = silu_f((f0 - mean[g]) * rstd[g] * gw[c0] + gb[c0]);
      float v1 = silu_f((f1 - mean[g]) * rstd[g] * gw[c0 + 1] + gb[c0 + 1]);
      a0 = fmaf(v0, rw[c0], a0);       a0 = fmaf(v1, rw[c0 + 1], a0);
      a1 = fmaf(v0, rw[64 + c0], a1);  a1 = fmaf(v1, rw[64 + c0 + 1], a1);
      a2 = fmaf(v0, rw[128 + c0], a2); a2 = fmaf(v1, rw[128 + c0 + 1], a2);
    }
  }
  Y[(size_t)(b * 3 + 0) * 25600 + pix] = a0;
  Y[(size_t)(b * 3 + 1) * 25600 + pix] = a1;
  Y[(size_t)(b * 3 + 2) * 25600 + pix] = a2;
}

// ---- feamap: argx = conv(Y, fw, stride 4)/16, first 3 channels ------------
__global__ void feamap_k(const float* __restrict__ Y, const float* __restrict__ fw,
                         float* __restrict__ argx)
{
  int idx = blockIdx.x * 256 + threadIdx.x;
  if (idx >= 16 * 3 * 1600) return;
  int b  = idx / (3 * 1600);
  int o  = (idx / 1600) % 3;
  int ij = idx % 1600;
  int i = ij / 40, j = ij - i * 40;
  float s = 0.f;
  #pragma unroll
  for (int c = 0; c < 3; ++c)
    #pragma unroll
    for (int u = 0; u < 4; ++u)
      #pragma unroll
      for (int v = 0; v < 4; ++v)
        s += Y[((size_t)(b * 3 + c) * 160 + (4 * i + u)) * 160 + (4 * j + v)]
             * fw[((o * 3 + c) * 4 + u) * 4 + v];
  argx[idx] = s * (1.f / 16.f);
}

__global__ void nz_k(const float* __restrict__ attn, float* __restrict__ nzinv) {
  int idx = blockIdx.x * 256 + threadIdx.x;
  if (idx >= 16 * 3 * 256) return;
  const float* p = attn + (size_t)idx * 16;
  int c = 0;
  #pragma unroll
  for (int k = 0; k < 16; ++k) c += (p[k] != 0.f);
  nzinv[idx] = 1.f / ((float)c + 1e-5f);
}

__global__ void final_k(const float* __restrict__ Y, const float* __restrict__ attn,
                        const float* __restrict__ nzinv, const float* __restrict__ argx,
                        float* __restrict__ out)
{
  int idx = blockIdx.x * 256 + threadIdx.x;
  if (idx >= 16 * 3 * 25600) return;
  int bc  = idx / 25600;
  int pix = idx - bc * 25600;
  int y = pix / 160, x = pix - y * 160;
  int l  = (y / 10) * 16 + (x / 10);
  int pi = y % 10,  pj = x % 10;
  const float* ar = attn + ((size_t)bc * 256 + l) * 16;
  const float* ax = argx + (size_t)bc * 1600;
  float inv = nzinv[bc * 256 + l];
  float corr = 0.f;
  #pragma unroll
  for (int k = 0; k < 16; ++k)
    corr += ar[k] * ax[((k >> 2) * 10 + pi) * 40 + ((k & 3) * 10 + pj)];
  float yv = Y[idx];
  out[idx] = yv * (1.f + corr * inv);
}

// ---------------------------------------------------------------------------
extern "C" void kernel_launch(void* const* d_in, const int* in_sizes, int n_in,
                              void* d_out, int out_size, void* d_ws, size_t ws_size,
                              hipStream_t stream)
{
  const float* attn = (const float*)d_in[0];
  const float* hid  = (const float*)d_in[1];
  const float* enc1 = (const float*)d_in[2];
  const float* d0w  = (const float*)d_in[3];
  const float* d0b  = (const float*)d_in[4];
  const float* d0gw = (const float*)d_in[5];
  const float* d0gb = (const float*)d_in[6];
  const float* d1w  = (const float*)d_in[7];
  const float* d1b  = (const float*)d_in[8];
  const float* d1gw = (const float*)d_in[9];
  const float* d1gb = (const float*)d_in[10];
  const float* d2w  = (const float*)d_in[11];
  const float* d2b  = (const float*)d_in[12];
  const float* d2gw = (const float*)d_in[13];
  const float* d2gb = (const float*)d_in[14];
  const float* d3w  = (const float*)d_in[15];
  const float* d3b  = (const float*)d_in[16];
  const float* d3gw = (const float*)d_in[17];
  const float* d3gb = (const float*)d_in[18];
  const float* rw   = (const float*)d_in[19];
  const float* rb   = (const float*)d_in[20];
  const float* fw   = (const float*)d_in[21];

  float* ws = (float*)d_ws;
  size_t o = 0;
  float* bufA  = ws + o; o += (size_t)16 * 64 * 80 * 80;         // Y+argx+nzv
  float* Abff  = ws + o; o += (size_t)16 * 82 * 82 * 64 / 2;     // Abf
  float* Bbff  = ws + o; o += (size_t)16 * 82 * 82 * 64 / 2;     // Bbf
  float* Cbff  = ws + o; o += (size_t)16 * 162 * 162 * 64 / 2;   // Cbf
  float* Dbff  = ws + o; o += (size_t)16 * 162 * 162 * 64 / 2;   // Dbf
  float* hidPf = ws + o; o += (size_t)16 * 42 * 42 * 64 / 2;     // hidP
  float* st    = ws + o; o += 4 * 512;                           // slotted stats
  float* w0f   = ws + o; o += (size_t)72 * 256 * 8 / 2;
  float* w1f   = ws + o; o += (size_t)72 * 64 * 8 / 2;
  float* w2f   = ws + o; o += (size_t)72 * 256 * 8 / 2;
  float* w3f   = ws + o; o += (size_t)72 * 64 * 8 / 2;

  ushort* Abf  = (ushort*)Abff;
  ushort* Bbf  = (ushort*)Bbff;
  ushort* Cbf  = (ushort*)Cbff;
  ushort* Dbf  = (ushort*)Dbff;
  ushort* hidP = (ushort*)hidPf;
  float*  Y    = bufA;
  float*  argx = bufA + (size_t)16 * 3 * 25600;
  float*  nzv  = argx + (size_t)16 * 3 * 1600;
  ushort* wr0  = (ushort*)w0f;
  ushort* wr1  = (ushort*)w1f;
  ushort* wr2  = (ushort*)w2f;
  ushort* wr3  = (ushort*)w3f;

  zero_k<<<8, 256, 0, stream>>>(st, 4 * 512);

  repackw_k<256><<<(256 * 576 + 255) / 256, 256, 0, stream>>>(d0w, wr0);
  repackw_k<64><<<(64 * 576 + 255) / 256, 256, 0, stream>>>(d1w, wr1);
  repackw_k<256><<<(256 * 576 + 255) / 256, 256, 0, stream>>>(d2w, wr2);
  repackw_k<64><<<(64 * 576 + 255) / 256, 256, 0, stream>>>(d3w, wr3);

  // borders (zeroed every call; convs write interiors only)
  border_k<42, 42><<<(16 * 42 * 42 + 255) / 256, 256, 0, stream>>>(hidP);
  border_k<82, 82><<<(16 * 82 * 82 + 255) / 256, 256, 0, stream>>>(Abf);
  border_k<82, 82><<<(16 * 82 * 82 + 255) / 256, 256, 0, stream>>>(Bbf);
  border_k<162, 162><<<(16 * 162 * 162 + 255) / 256, 256, 0, stream>>>(Cbf);

  // pad hid -> hidP (NHWC bf16)
  pad_k<1600, 40><<<16 * 7, 256, 0, stream>>>(hid, hidP);

  // stage 0: conv(hidP)+PS -> Abf (pre-norm), stats st0
  convm_k<40, 40, 40, 3, 10, 256, true, 1, 1>
    <<<dim3(4, 16 * 4), 256, 0, stream>>>((const uint4*)hidP, wr0, d0b, Abf,
                                          st + 0 * 512);
  // actn1: in-place GN+SiLU on Abf
  actn_k<80, 80, false><<<(16 * 6400 + 255) / 256, 256, 0, stream>>>(
      Abf, st + 0 * 512, d0gw, d0gb, nullptr);

  // stage 1: conv(Abf) -> Bbf (pre-norm), stats st1
  convm_k<80, 80, 16, 1, 10, 64, false, 2, 2>
    <<<dim3(40, 16), 256, 0, stream>>>((const uint4*)Abf, wr1, d1b, Bbf,
                                       st + 1 * 512);
  // actn2: in-place GN+SiLU on Bbf
  actn_k<80, 80, false><<<(16 * 6400 + 255) / 256, 256, 0, stream>>>(
      Bbf, st + 1 * 512, d1gw, d1gb, nullptr);

  // stage 2: conv(Bbf)+PS -> Cbf (pre-norm), stats st2
  convm_k<80, 80, 16, 1, 10, 256, true, 2, 2>
    <<<dim3(40, 16 * 4), 256, 0, stream>>>((const uint4*)Bbf, wr2, d2b, Cbf,
                                           st + 2 * 512);
  // actn3: in-place GN+SiLU + enc1 on Cbf
  actn_k<160, 160, true><<<(16 * 25600 + 255) / 256, 256, 0, stream>>>(
      Cbf, st + 2 * 512, d2gw, d2gb, enc1);

  // stage 3: conv(Cbf) -> Dbf (pre-norm), stats st3
  convm_k<160, 160, 16, 1, 10, 64, false, 2, 2>
    <<<dim3(160, 16), 256, 0, stream>>>((const uint4*)Cbf, wr3, d3b, Dbf,
                                        st + 3 * 512);

  // readout: Y = 1x1conv(GN_SiLU(Dbf))
  readout_k<<<(16 * 25600 + 255) / 256, 256, 0, stream>>>(Dbf, st + 3 * 512,
      d3gw, d3gb, rw, rb, Y);

  feamap_k<<<(16 * 3 * 1600 + 255) / 256, 256, 0, stream>>>(Y, fw, argx);
  nz_k<<<(16 * 3 * 256 + 255) / 256, 256, 0, stream>>>(attn, nzv);
  final_k<<<(16 * 3 * 25600 + 255) / 256, 256, 0, stream>>>(Y, attn, nzv, argx,
      (float*)d_out);
}

// Round 13
// 310.361 us; speedup vs baseline: 1.0937x; 1.0937x over previous
//
#include <hip/hip_runtime.h>

// ---------------------------------------------------------------------------
// SimVP Decoder, round 13: R12 dataflow (all intermediates padded NHWC bf16,
// pre-norm; in-place GN+SiLU) with COALESCED (pixel,chunk) lane decomposition
// for actn_k and readout_k.
// R12 post-mortem: per-thread 8-chunk loops made every wave instruction a
// 16B@128B-stride gather (64 lines/instr, L1 thrash) -> actn3 ran 103us at
// 2.3 TB/s. Now lane=(pixel*8+slot): wave = 8 pixels x 128B = 1KB contiguous.
// Conv kernels identical to R11/R12 (passed): single-staged row strip,
// 36 named weight v8s resident, barrier-free row-pair loop, R8 stats path.
// ---------------------------------------------------------------------------

#define DEVFN static __device__ __forceinline__

typedef short v8s __attribute__((ext_vector_type(8)));
typedef float v4f __attribute__((ext_vector_type(4)));

DEVFN float silu_f(float t) { return t / (1.f + __expf(-t)); }

DEVFN ushort f2bf(float x) {
  union { float f; unsigned u; } t; t.f = x;
  unsigned r = t.u + 0x7FFFu + ((t.u >> 16) & 1u);
  return (ushort)(r >> 16);
}

DEVFN float bf2f(unsigned u) {
  union { unsigned i; float f; } t; t.i = u << 16; return t.f;
}

__global__ void zero_k(float* __restrict__ p, int n) {
  int i = blockIdx.x * 256 + threadIdx.x;
  if (i < n) p[i] = 0.f;
}

// ---- weight repack: [OC][64][3][3] f32 -> bf16 [kc=tap*8+ic/8][OC][8] -----
template<int OC>
__global__ void repackw_k(const float* __restrict__ src, ushort* __restrict__ dst) {
  int i = blockIdx.x * 256 + threadIdx.x;
  if (i >= OC * 576) return;
  int oc = i / 576, r = i - oc * 576;      // r = ic*9 + tap
  int ic = r / 9, tap = r - ic * 9;
  int kc = tap * 8 + (ic >> 3), j = ic & 7;
  dst[((size_t)kc * OC + oc) * 8 + j] = f2bf(src[i]);
}

// ---- zero the 1-px border of a padded NHWC bf16 buffer --------------------
template<int HP, int WP>
__global__ void border_k(ushort* __restrict__ outP) {
  int idx = blockIdx.x * 256 + threadIdx.x;
  if (idx >= 16 * HP * WP) return;
  int p = idx % (HP * WP);
  int y = p / WP, x = p - y * WP;
  if (y == 0 || y == HP - 1 || x == 0 || x == WP - 1) {
    uint4 z = {0u, 0u, 0u, 0u};
    uint4* dst = (uint4*)(outP + (size_t)idx * 64);
    #pragma unroll
    for (int k = 0; k < 8; ++k) dst[k] = z;
  }
}

// ---- slot-summed GN stats -> (mean, rstd) ---------------------------------
DEVFN void gn_stats(const float* __restrict__ st, int bg, float N,
                    float& mean, float& rstd) {
  float s = 0.f, q = 0.f;
  #pragma unroll
  for (int sl = 0; sl < 8; ++sl) {
    s += st[sl * 64 + bg * 2 + 0];
    q += st[sl * 64 + bg * 2 + 1];
  }
  float m = s / N;
  mean = m;
  rstd = rsqrtf(q / N - m * m + 1e-5f);
}

// ---- pad/transpose: NCHW f32 -> padded NHWC bf16 (raw copy, for hid) ------
template<int HW_TOT, int WOUT>
__global__ __launch_bounds__(256)
void pad_k(const float* __restrict__ in, ushort* __restrict__ outP)
{
  constexpr int HOUT = HW_TOT / WOUT;
  constexpr int WP = WOUT + 2, HP = HOUT + 2;
  __shared__ uint4 sT[256 * 8];
  const int tid = threadIdx.x;
  constexpr int NBLK = (HW_TOT + 255) / 256;
  const int b  = blockIdx.x / NBLK;
  const int p0 = (blockIdx.x - b * NBLK) * 256;
  const int px = p0 + tid;

  if (px < HW_TOT) {
    const float* ip = in + (size_t)b * 64 * HW_TOT + px;
    #pragma unroll 2
    for (int cc = 0; cc < 8; ++cc) {
      unsigned w[4];
      #pragma unroll
      for (int jp = 0; jp < 4; ++jp) {
        float v0 = ip[(size_t)(cc * 8 + jp * 2) * HW_TOT];
        float v1 = ip[(size_t)(cc * 8 + jp * 2 + 1) * HW_TOT];
        w[jp] = (unsigned)f2bf(v0) | ((unsigned)f2bf(v1) << 16);
      }
      uint4 pk = {w[0], w[1], w[2], w[3]};
      sT[tid * 8 + (cc ^ (tid & 7))] = pk;
    }
  }
  __syncthreads();
  const int o = tid & 7, pr = tid >> 3;
  #pragma unroll
  for (int i = 0; i < 8; ++i) {
    int p = i * 32 + pr;
    int gpx = p0 + p;
    if (gpx < HW_TOT) {
      int y = gpx / WOUT, x = gpx - y * WOUT;
      uint4 val = sT[p * 8 + (o ^ (p & 7))];
      *(uint4*)(outP + (((size_t)(b * HP) + y + 1) * WP + (x + 1)) * 64 + o * 8) = val;
    }
  }
}

// ---- in-place GN+SiLU (+enc1), lane = (pixel, chunk-slot) -----------------
// Wave instruction = 8 pixels x 128B = 1KB contiguous.
template<int HOUT, int WOUT, bool ADD>
__global__ __launch_bounds__(256)
void actn_k(ushort* __restrict__ buf, const float* __restrict__ st,
            const float* __restrict__ gw, const float* __restrict__ gb,
            const float* __restrict__ addsrc)
{
  constexpr int HW = HOUT * WOUT;
  constexpr int WP = WOUT + 2, HP = HOUT + 2;
  int t = blockIdx.x * 256 + threadIdx.x;
  int gp = t >> 3;
  if (gp >= 16 * HW) return;
  const int slot = t & 7;
  int b = gp / HW, pix = gp - b * HW;
  int y = pix / WOUT, x = pix - y * WOUT;

  const float N = 32.f * HW;
  const int g = slot >> 2;                 // channels slot*8..slot*8+7, one group
  float mean, rstd;
  gn_stats(st, b * 2 + g, N, mean, rstd);

  uint4* pv = (uint4*)(buf + (((size_t)(b * HP) + y + 1) * WP + (x + 1)) * 64
                       + slot * 8);
  uint4 v = *pv;
  const float* ap = ADD ? (addsrc + (size_t)(b * 64 + slot * 8) * HW + pix)
                        : nullptr;
  unsigned r[4];
  #pragma unroll
  for (int k = 0; k < 4; ++k) {
    unsigned w = (k == 0) ? v.x : (k == 1) ? v.y : (k == 2) ? v.z : v.w;
    const int c0 = slot * 8 + k * 2;
    float f0 = bf2f(w & 0xffffu), f1 = bf2f(w >> 16);
    float r0 = silu_f((f0 - mean) * rstd * gw[c0] + gb[c0]);
    float r1 = silu_f((f1 - mean) * rstd * gw[c0 + 1] + gb[c0 + 1]);
    if (ADD) {
      r0 += ap[(size_t)(2 * k) * HW];
      r1 += ap[(size_t)(2 * k + 1) * HW];
    }
    r[k] = (unsigned)f2bf(r0) | ((unsigned)f2bf(r1) << 16);
  }
  uint4 pk = {r[0], r[1], r[2], r[3]};
  *pv = pk;
}

// ---- MFMA implicit-GEMM 3x3 conv, single-staged row strip -----------------
// In: padded NHWC bf16. Out: padded NHWC bf16, PRE-NORM (stats fused).

#define FE18(M) M(0) M(1) M(2) M(3) M(4) M(5) M(6) M(7) M(8) M(9) M(10) \
                M(11) M(12) M(13) M(14) M(15) M(16) M(17)

#define WDL(t) \
  v8s Wa##t = ((const v8s*)wrep)[(size_t)((t) * 4 + sub) * OCT + ocbase + lx]; \
  v8s Wb##t = ((const v8s*)wrep)[(size_t)((t) * 4 + sub) * OCT + ocbase + 16 + lx];

#define KST(t) { \
    const int col_ = xb + lx + (((t) >> 1) % 3); \
    v8s b_ = __builtin_bit_cast(v8s, sQ[((rbase + wrow + (t) / 6) * LWS + col_) * 8 + \
                                        (((((t) & 1) * 4 + sub)) ^ (col_ & 7))]); \
    a0 = __builtin_amdgcn_mfma_f32_16x16x32_bf16(Wa##t, b_, a0, 0, 0, 0); \
    a1 = __builtin_amdgcn_mfma_f32_16x16x32_bf16(Wb##t, b_, a1, 0, 0, 0); }

template<int HIN, int WIN, int WT, int NG, int RPB, int OCT, bool PSF,
         int WEU_MIN, int WEU_MAX>
__global__
__attribute__((amdgpu_flat_work_group_size(256, 256),
               amdgpu_waves_per_eu(WEU_MIN, WEU_MAX)))
void convm_k(const uint4* __restrict__ inP, const ushort* __restrict__ wrep,
             const float* __restrict__ bias, ushort* __restrict__ outP,
             float* __restrict__ stp)
{
  constexpr int HP = HIN + 2, WP = WIN + 2;
  constexpr int HPo = PSF ? (2 * HIN + 2) : (HIN + 2);
  constexpr int WPo = PSF ? (2 * WIN + 2) : (WIN + 2);
  constexpr int LH = RPB + 2, LW = WT + 2;
  constexpr int NOCB = OCT / 64;
  constexpr int LRD = (NG * 16 + 2 > LW) ? (NG * 16 + 2) : LW;
  constexpr int LWS = (LRD + 7) & ~7;      // multiple of 8: (pix&7)==(col&7)
  constexpr int NCHUNK = LH * LWS * 8;
  static_assert(NCHUNK % 256 == 0, "staging must tile evenly");
  constexpr int STK = NCHUNK / 256;
  __shared__ uint4 sQ[NCHUNK];
  __shared__ float red[4][2];

  const int tid  = threadIdx.x;
  const int lane = tid & 63;
  const int wave = tid >> 6;
  const int sub  = lane >> 4;
  const int lx   = lane & 15;
  const int wrow = wave >> 1;              // row within pair
  const int b    = blockIdx.y / NOCB;
  const int ocb  = blockIdx.y - b * NOCB;
  constexpr int NTX = WIN / WT;
  const int tx    = blockIdx.x % NTX;
  const int ych   = blockIdx.x / NTX;
  const int x0    = tx * WT;
  const int ybase = ych * RPB;
  const int ocbase = ocb * 64 + (wave & 1) * 32;

  FE18(WDL)

  const v4f bi0 = *(const v4f*)&bias[ocbase + sub * 4];
  const v4f bi1 = *(const v4f*)&bias[ocbase + 16 + sub * 4];

  // stage the whole (RPB+2)-row strip once (batched loads, one wait)
  const uint4* gbase = inP + ((size_t)(b * HP + ybase) * WP + x0) * 8;
  uint4 stg[STK];
  #pragma unroll
  for (int k = 0; k < STK; ++k) {
    int q = tid + k * 256;
    int p = q >> 3, cc = q & 7;
    int r = p / LWS, cx = p - r * LWS;
    stg[k] = gbase[((size_t)r * WP + cx) * 8 + cc];
  }
  #pragma unroll
  for (int k = 0; k < STK; ++k) {
    int q = tid + k * 256;
    int p = q >> 3, cc = q & 7;
    int cx = p - (p / LWS) * LWS;
    sQ[p * 8 + (cc ^ (cx & 7))] = stg[k];
  }
  __syncthreads();

  float sA = 0.f, qA = 0.f;

  for (int it = 0; it < RPB / 2; ++it) {
    const int rbase = it * 2;
    const int y = ybase + rbase + wrow;
    for (int xg = 0; xg < NG; ++xg) {
      const int xb = xg * 16;
      v4f a0 = bi0, a1 = bi1;
      FE18(KST)
      const int x = x0 + xb + lx;
      if ((NG * 16 == WT) || (x < WIN)) {
        if (!PSF) {
          const size_t pbase =
            (((size_t)(b * HPo) + y + 1) * WPo + (x + 1)) * 64 + (wave & 1) * 32;
          #pragma unroll
          for (int s = 0; s < 2; ++s) {
            const v4f a = s ? a1 : a0;
            uint2 pk;
            pk.x = (unsigned)f2bf(a[0]) | ((unsigned)f2bf(a[1]) << 16);
            pk.y = (unsigned)f2bf(a[2]) | ((unsigned)f2bf(a[3]) << 16);
            *(uint2*)(outP + pbase + s * 16 + sub * 4) = pk;
            #pragma unroll
            for (int j = 0; j < 4; ++j) { sA += a[j]; qA += a[j] * a[j]; }
          }
        } else {
          #pragma unroll
          for (int s = 0; s < 2; ++s) {
            const v4f a = s ? a1 : a0;
            #pragma unroll
            for (int j = 0; j < 4; ++j) {
              int oc = ocbase + s * 16 + sub * 4 + j;
              int c = oc >> 2, rr = (oc >> 1) & 1, ss = oc & 1;
              outP[(((size_t)(b * HPo) + 2 * y + rr + 1) * WPo
                    + (2 * x + ss + 1)) * 64 + c] = f2bf(a[j]);
              sA += a[j]; qA += a[j] * a[j];
            }
          }
        }
      }
    }
  }

  // GroupNorm stats (f32 accumulators, exact)
  #pragma unroll
  for (int o = 32; o >= 1; o >>= 1) {
    sA += __shfl_down(sA, o);
    qA += __shfl_down(qA, o);
  }
  if (lane == 0) { red[wave][0] = sA; red[wave][1] = qA; }
  __syncthreads();
  if (tid == 0) {
    float* basep = stp + ((blockIdx.x ^ blockIdx.y) & 7) * 64;
    if (PSF) {
      int g = ocb >> 1;
      atomicAdd(&basep[(b * 2 + g) * 2 + 0],
                red[0][0] + red[1][0] + red[2][0] + red[3][0]);
      atomicAdd(&basep[(b * 2 + g) * 2 + 1],
                red[0][1] + red[1][1] + red[2][1] + red[3][1]);
    } else {
      atomicAdd(&basep[(b * 2 + 0) * 2 + 0], red[0][0] + red[2][0]);
      atomicAdd(&basep[(b * 2 + 0) * 2 + 1], red[0][1] + red[2][1]);
      atomicAdd(&basep[(b * 2 + 1) * 2 + 0], red[1][0] + red[3][0]);
      atomicAdd(&basep[(b * 2 + 1) * 2 + 1], red[1][1] + red[3][1]);
    }
  }
}

// ---- readout, lane = (pixel, chunk-slot); 8-lane shuffle reduction --------
__global__ __launch_bounds__(256)
void readout_k(const ushort* __restrict__ Dp, const float* __restrict__ st,
               const float* __restrict__ gw, const float* __restrict__ gb,
               const float* __restrict__ rw, const float* __restrict__ rb,
               float* __restrict__ Y)
{
  int t = blockIdx.x * 256 + threadIdx.x;
  int gp = t >> 3;
  if (gp >= 16 * 25600) return;
  const int slot = t & 7;
  int b = gp / 25600, pix = gp - b * 25600;
  int y = pix / 160, x = pix - y * 160;
  const float N = 32.f * 25600.f;
  const int g = slot >> 2;
  float mean, rstd;
  gn_stats(st, b * 2 + g, N, mean, rstd);

  const uint4* p = (const uint4*)(Dp + (((size_t)(b * 162) + y + 1) * 162
                                        + (x + 1)) * 64 + slot * 8);
  uint4 v = *p;
  float a0 = 0.f, a1 = 0.f, a2 = 0.f;
  #pragma unroll
  for (int k = 0; k < 4; ++k) {
    unsigned w = (k == 0) ? v.x : (k == 1) ? v.y : (k == 2) ? v.z : v.w;
    const int c0 = slot * 8 + k * 2;
    float f0 = bf2f(w & 0xffffu), f1 = bf2f(w >> 16);
    float v0 = silu_f((f0 - mean) * rstd * gw[c0] + gb[c0]);
    float v1 = silu_f((f1 - mean) * rstd * gw[c0 + 1] + gb[c0 + 1]);
    a0 = fmaf(v0, rw[c0], a0);       a0 = fmaf(v1, rw[c0 + 1], a0);
    a1 = fmaf(v0, rw[64 + c0], a1);  a1 = fmaf(v1, rw[64 + c0 + 1], a1);
    a2 = fmaf(v0, rw[128 + c0], a2); a2 = fmaf(v1, rw[128 + c0 + 1], a2);
  }
  // reduce across the 8 slots of this pixel (8-aligned lane groups)
  #pragma unroll
  for (int m = 1; m < 8; m <<= 1) {
    a0 += __shfl_xor(a0, m);
    a1 += __shfl_xor(a1, m);
    a2 += __shfl_xor(a2, m);
  }
  if (slot == 0) {
    Y[(size_t)(b * 3 + 0) * 25600 + pix] = a0 + rb[0];
    Y[(size_t)(b * 3 + 1) * 25600 + pix] = a1 + rb[1];
    Y[(size_t)(b * 3 + 2) * 25600 + pix] = a2 + rb[2];
  }
}

// ---- feamap: argx = conv(Y, fw, stride 4)/16, first 3 channels ------------
__global__ void feamap_k(const float* __restrict__ Y, const float* __restrict__ fw,
                         float* __restrict__ argx)
{
  int idx = blockIdx.x * 256 + threadIdx.x;
  if (idx >= 16 * 3 * 1600) return;
  int b  = idx / (3 * 1600);
  int o  = (idx / 1600) % 3;
  int ij = idx % 1600;
  int i = ij / 40, j = ij - i * 40;
  float s = 0.f;
  #pragma unroll
  for (int c = 0; c < 3; ++c)
    #pragma unroll
    for (int u = 0; u < 4; ++u)
      #pragma unroll
      for (int v = 0; v < 4; ++v)
        s += Y[((size_t)(b * 3 + c) * 160 + (4 * i + u)) * 160 + (4 * j + v)]
             * fw[((o * 3 + c) * 4 + u) * 4 + v];
  argx[idx] = s * (1.f / 16.f);
}

__global__ void nz_k(const float* __restrict__ attn, float* __restrict__ nzinv) {
  int idx = blockIdx.x * 256 + threadIdx.x;
  if (idx >= 16 * 3 * 256) return;
  const float* p = attn + (size_t)idx * 16;
  int c = 0;
  #pragma unroll
  for (int k = 0; k < 16; ++k) c += (p[k] != 0.f);
  nzinv[idx] = 1.f / ((float)c + 1e-5f);
}

__global__ void final_k(const float* __restrict__ Y, const float* __restrict__ attn,
                        const float* __restrict__ nzinv, const float* __restrict__ argx,
                        float* __restrict__ out)
{
  int idx = blockIdx.x * 256 + threadIdx.x;
  if (idx >= 16 * 3 * 25600) return;
  int bc  = idx / 25600;
  int pix = idx - bc * 25600;
  int y = pix / 160, x = pix - y * 160;
  int l  = (y / 10) * 16 + (x / 10);
  int pi = y % 10,  pj = x % 10;
  const float* ar = attn + ((size_t)bc * 256 + l) * 16;
  const float* ax = argx + (size_t)bc * 1600;
  float inv = nzinv[bc * 256 + l];
  float corr = 0.f;
  #pragma unroll
  for (int k = 0; k < 16; ++k)
    corr += ar[k] * ax[((k >> 2) * 10 + pi) * 40 + ((k & 3) * 10 + pj)];
  float yv = Y[idx];
  out[idx] = yv * (1.f + corr * inv);
}

// ---------------------------------------------------------------------------
extern "C" void kernel_launch(void* const* d_in, const int* in_sizes, int n_in,
                              void* d_out, int out_size, void* d_ws, size_t ws_size,
                              hipStream_t stream)
{
  const float* attn = (const float*)d_in[0];
  const float* hid  = (const float*)d_in[1];
  const float* enc1 = (const float*)d_in[2];
  const float* d0w  = (const float*)d_in[3];
  const float* d0b  = (const float*)d_in[4];
  const float* d0gw = (const float*)d_in[5];
  const float* d0gb = (const float*)d_in[6];
  const float* d1w  = (const float*)d_in[7];
  const float* d1b  = (const float*)d_in[8];
  const float* d1gw = (const float*)d_in[9];
  const float* d1gb = (const float*)d_in[10];
  const float* d2w  = (const float*)d_in[11];
  const float* d2b  = (const float*)d_in[12];
  const float* d2gw = (const float*)d_in[13];
  const float* d2gb = (const float*)d_in[14];
  const float* d3w  = (const float*)d_in[15];
  const float* d3b  = (const float*)d_in[16];
  const float* d3gw = (const float*)d_in[17];
  const float* d3gb = (const float*)d_in[18];
  const float* rw   = (const float*)d_in[19];
  const float* rb   = (const float*)d_in[20];
  const float* fw   = (const float*)d_in[21];

  float* ws = (float*)d_ws;
  size_t o = 0;
  float* bufA  = ws + o; o += (size_t)16 * 64 * 80 * 80;         // Y+argx+nzv
  float* Abff  = ws + o; o += (size_t)16 * 82 * 82 * 64 / 2;     // Abf
  float* Bbff  = ws + o; o += (size_t)16 * 82 * 82 * 64 / 2;     // Bbf
  float* Cbff  = ws + o; o += (size_t)16 * 162 * 162 * 64 / 2;   // Cbf
  float* Dbff  = ws + o; o += (size_t)16 * 162 * 162 * 64 / 2;   // Dbf
  float* hidPf = ws + o; o += (size_t)16 * 42 * 42 * 64 / 2;     // hidP
  float* st    = ws + o; o += 4 * 512;                           // slotted stats
  float* w0f   = ws + o; o += (size_t)72 * 256 * 8 / 2;
  float* w1f   = ws + o; o += (size_t)72 * 64 * 8 / 2;
  float* w2f   = ws + o; o += (size_t)72 * 256 * 8 / 2;
  float* w3f   = ws + o; o += (size_t)72 * 64 * 8 / 2;

  ushort* Abf  = (ushort*)Abff;
  ushort* Bbf  = (ushort*)Bbff;
  ushort* Cbf  = (ushort*)Cbff;
  ushort* Dbf  = (ushort*)Dbff;
  ushort* hidP = (ushort*)hidPf;
  float*  Y    = bufA;
  float*  argx = bufA + (size_t)16 * 3 * 25600;
  float*  nzv  = argx + (size_t)16 * 3 * 1600;
  ushort* wr0  = (ushort*)w0f;
  ushort* wr1  = (ushort*)w1f;
  ushort* wr2  = (ushort*)w2f;
  ushort* wr3  = (ushort*)w3f;

  zero_k<<<8, 256, 0, stream>>>(st, 4 * 512);

  repackw_k<256><<<(256 * 576 + 255) / 256, 256, 0, stream>>>(d0w, wr0);
  repackw_k<64><<<(64 * 576 + 255) / 256, 256, 0, stream>>>(d1w, wr1);
  repackw_k<256><<<(256 * 576 + 255) / 256, 256, 0, stream>>>(d2w, wr2);
  repackw_k<64><<<(64 * 576 + 255) / 256, 256, 0, stream>>>(d3w, wr3);

  // borders (zeroed every call; convs write interiors only)
  border_k<42, 42><<<(16 * 42 * 42 + 255) / 256, 256, 0, stream>>>(hidP);
  border_k<82, 82><<<(16 * 82 * 82 + 255) / 256, 256, 0, stream>>>(Abf);
  border_k<82, 82><<<(16 * 82 * 82 + 255) / 256, 256, 0, stream>>>(Bbf);
  border_k<162, 162><<<(16 * 162 * 162 + 255) / 256, 256, 0, stream>>>(Cbf);

  // pad hid -> hidP (NHWC bf16)
  pad_k<1600, 40><<<16 * 7, 256, 0, stream>>>(hid, hidP);

  // stage 0: conv(hidP)+PS -> Abf (pre-norm), stats st0
  convm_k<40, 40, 40, 3, 10, 256, true, 1, 1>
    <<<dim3(4, 16 * 4), 256, 0, stream>>>((const uint4*)hidP, wr0, d0b, Abf,
                                          st + 0 * 512);
  // actn1: in-place GN+SiLU on Abf
  actn_k<80, 80, false><<<16 * 6400 * 8 / 256, 256, 0, stream>>>(
      Abf, st + 0 * 512, d0gw, d0gb, nullptr);

  // stage 1: conv(Abf) -> Bbf (pre-norm), stats st1
  convm_k<80, 80, 16, 1, 10, 64, false, 2, 2>
    <<<dim3(40, 16), 256, 0, stream>>>((const uint4*)Abf, wr1, d1b, Bbf,
                                       st + 1 * 512);
  // actn2: in-place GN+SiLU on Bbf
  actn_k<80, 80, false><<<16 * 6400 * 8 / 256, 256, 0, stream>>>(
      Bbf, st + 1 * 512, d1gw, d1gb, nullptr);

  // stage 2: conv(Bbf)+PS -> Cbf (pre-norm), stats st2
  convm_k<80, 80, 16, 1, 10, 256, true, 2, 2>
    <<<dim3(40, 16 * 4), 256, 0, stream>>>((const uint4*)Bbf, wr2, d2b, Cbf,
                                           st + 2 * 512);
  // actn3: in-place GN+SiLU + enc1 on Cbf
  actn_k<160, 160, true><<<16 * 25600 * 8 / 256, 256, 0, stream>>>(
      Cbf, st + 2 * 512, d2gw, d2gb, enc1);

  // stage 3: conv(Cbf) -> Dbf (pre-norm), stats st3
  convm_k<160, 160, 16, 1, 10, 64, false, 2, 2>
    <<<dim3(160, 16), 256, 0, stream>>>((const uint4*)Cbf, wr3, d3b, Dbf,
                                        st + 3 * 512);

  // readout: Y = 1x1conv(GN_SiLU(Dbf))
  readout_k<<<16 * 25600 * 8 / 256, 256, 0, stream>>>(Dbf, st + 3 * 512,
      d3gw, d3gb, rw, rb, Y);

  feamap_k<<<(16 * 3 * 1600 + 255) / 256, 256, 0, stream>>>(Y, fw, argx);
  nz_k<<<(16 * 3 * 256 + 255) / 256, 256, 0, stream>>>(attn, nzv);
  final_k<<<(16 * 3 * 25600 + 255) / 256, 256, 0, stream>>>(Y, attn, nzv, argx,
      (float*)d_out);
}

// Round 14
// 307.216 us; speedup vs baseline: 1.1049x; 1.0102x over previous
//
#include <hip/hip_runtime.h>

// ---------------------------------------------------------------------------
// SimVP Decoder, round 14: R13 + fused enc1-transpose act kernel (actne_k).
// R13 post-mortem: actn3's enc1 addend was a stride-HW scatter (8 lines per
// wave instruction, 32B/line used) -> 74us at 1.74 TB/s. Now enc1 is staged
// through a 64KB f32 LDS tile with NCHW-coalesced loads (pad_k pattern),
// then consumed by the proven (pixel,slot) uint4 GN+SiLU phase. Same math.
// Everything else identical to R13 (passed): padded NHWC bf16 pre-norm
// intermediates, single-staged-strip MFMA convs with resident weights,
// R8 slot-spread stats.
// ---------------------------------------------------------------------------

#define DEVFN static __device__ __forceinline__

typedef short v8s __attribute__((ext_vector_type(8)));
typedef float v4f __attribute__((ext_vector_type(4)));

DEVFN float silu_f(float t) { return t / (1.f + __expf(-t)); }

DEVFN ushort f2bf(float x) {
  union { float f; unsigned u; } t; t.f = x;
  unsigned r = t.u + 0x7FFFu + ((t.u >> 16) & 1u);
  return (ushort)(r >> 16);
}

DEVFN float bf2f(unsigned u) {
  union { unsigned i; float f; } t; t.i = u << 16; return t.f;
}

__global__ void zero_k(float* __restrict__ p, int n) {
  int i = blockIdx.x * 256 + threadIdx.x;
  if (i < n) p[i] = 0.f;
}

// ---- weight repack: [OC][64][3][3] f32 -> bf16 [kc=tap*8+ic/8][OC][8] -----
template<int OC>
__global__ void repackw_k(const float* __restrict__ src, ushort* __restrict__ dst) {
  int i = blockIdx.x * 256 + threadIdx.x;
  if (i >= OC * 576) return;
  int oc = i / 576, r = i - oc * 576;      // r = ic*9 + tap
  int ic = r / 9, tap = r - ic * 9;
  int kc = tap * 8 + (ic >> 3), j = ic & 7;
  dst[((size_t)kc * OC + oc) * 8 + j] = f2bf(src[i]);
}

// ---- zero the 1-px border of a padded NHWC bf16 buffer --------------------
template<int HP, int WP>
__global__ void border_k(ushort* __restrict__ outP) {
  int idx = blockIdx.x * 256 + threadIdx.x;
  if (idx >= 16 * HP * WP) return;
  int p = idx % (HP * WP);
  int y = p / WP, x = p - y * WP;
  if (y == 0 || y == HP - 1 || x == 0 || x == WP - 1) {
    uint4 z = {0u, 0u, 0u, 0u};
    uint4* dst = (uint4*)(outP + (size_t)idx * 64);
    #pragma unroll
    for (int k = 0; k < 8; ++k) dst[k] = z;
  }
}

// ---- slot-summed GN stats -> (mean, rstd) ---------------------------------
DEVFN void gn_stats(const float* __restrict__ st, int bg, float N,
                    float& mean, float& rstd) {
  float s = 0.f, q = 0.f;
  #pragma unroll
  for (int sl = 0; sl < 8; ++sl) {
    s += st[sl * 64 + bg * 2 + 0];
    q += st[sl * 64 + bg * 2 + 1];
  }
  float m = s / N;
  mean = m;
  rstd = rsqrtf(q / N - m * m + 1e-5f);
}

// ---- pad/transpose: NCHW f32 -> padded NHWC bf16 (raw copy, for hid) ------
template<int HW_TOT, int WOUT>
__global__ __launch_bounds__(256)
void pad_k(const float* __restrict__ in, ushort* __restrict__ outP)
{
  constexpr int HOUT = HW_TOT / WOUT;
  constexpr int WP = WOUT + 2, HP = HOUT + 2;
  __shared__ uint4 sT[256 * 8];
  const int tid = threadIdx.x;
  constexpr int NBLK = (HW_TOT + 255) / 256;
  const int b  = blockIdx.x / NBLK;
  const int p0 = (blockIdx.x - b * NBLK) * 256;
  const int px = p0 + tid;

  if (px < HW_TOT) {
    const float* ip = in + (size_t)b * 64 * HW_TOT + px;
    #pragma unroll 2
    for (int cc = 0; cc < 8; ++cc) {
      unsigned w[4];
      #pragma unroll
      for (int jp = 0; jp < 4; ++jp) {
        float v0 = ip[(size_t)(cc * 8 + jp * 2) * HW_TOT];
        float v1 = ip[(size_t)(cc * 8 + jp * 2 + 1) * HW_TOT];
        w[jp] = (unsigned)f2bf(v0) | ((unsigned)f2bf(v1) << 16);
      }
      uint4 pk = {w[0], w[1], w[2], w[3]};
      sT[tid * 8 + (cc ^ (tid & 7))] = pk;
    }
  }
  __syncthreads();
  const int o = tid & 7, pr = tid >> 3;
  #pragma unroll
  for (int i = 0; i < 8; ++i) {
    int p = i * 32 + pr;
    int gpx = p0 + p;
    if (gpx < HW_TOT) {
      int y = gpx / WOUT, x = gpx - y * WOUT;
      uint4 val = sT[p * 8 + (o ^ (p & 7))];
      *(uint4*)(outP + (((size_t)(b * HP) + y + 1) * WP + (x + 1)) * 64 + o * 8) = val;
    }
  }
}

// ---- in-place GN+SiLU (no addend), lane = (pixel, chunk-slot) -------------
template<int HOUT, int WOUT>
__global__ __launch_bounds__(256)
void actn_k(ushort* __restrict__ buf, const float* __restrict__ st,
            const float* __restrict__ gw, const float* __restrict__ gb)
{
  constexpr int HW = HOUT * WOUT;
  constexpr int WP = WOUT + 2, HP = HOUT + 2;
  int t = blockIdx.x * 256 + threadIdx.x;
  int gp = t >> 3;
  if (gp >= 16 * HW) return;
  const int slot = t & 7;
  int b = gp / HW, pix = gp - b * HW;
  int y = pix / WOUT, x = pix - y * WOUT;

  const float N = 32.f * HW;
  const int g = slot >> 2;
  float mean, rstd;
  gn_stats(st, b * 2 + g, N, mean, rstd);

  uint4* pv = (uint4*)(buf + (((size_t)(b * HP) + y + 1) * WP + (x + 1)) * 64
                       + slot * 8);
  uint4 v = *pv;
  unsigned r[4];
  #pragma unroll
  for (int k = 0; k < 4; ++k) {
    unsigned w = (k == 0) ? v.x : (k == 1) ? v.y : (k == 2) ? v.z : v.w;
    const int c0 = slot * 8 + k * 2;
    float f0 = bf2f(w & 0xffffu), f1 = bf2f(w >> 16);
    float r0 = silu_f((f0 - mean) * rstd * gw[c0] + gb[c0]);
    float r1 = silu_f((f1 - mean) * rstd * gw[c0 + 1] + gb[c0 + 1]);
    r[k] = (unsigned)f2bf(r0) | ((unsigned)f2bf(r1) << 16);
  }
  uint4 pk = {r[0], r[1], r[2], r[3]};
  *pv = pk;
}

// ---- in-place GN+SiLU + enc1 via f32 LDS transpose (for actn3) ------------
// Block = 256 pixels x 64 channels. Phase A: enc1 NCHW-coalesced -> 64KB f32
// LDS (swizzled c^(p&31)). Phase B: (pixel,slot) uint4 GN+SiLU+add.
__global__ __launch_bounds__(256)
void actne_k(ushort* __restrict__ buf, const float* __restrict__ st,
             const float* __restrict__ gw, const float* __restrict__ gb,
             const float* __restrict__ addsrc)
{
  constexpr int HW = 25600, WOUT = 160, WP = 162, HP = 162;
  __shared__ float sE[256 * 64];           // 64 KB
  const int tid = threadIdx.x;
  const int b   = blockIdx.x / 100;
  const int p0  = (blockIdx.x - b * 100) * 256;

  // phase A: stage enc1 for these 256 pixels (coalesced per-channel reads)
  {
    const float* ip = addsrc + (size_t)b * 64 * HW + p0 + tid;
    float* row = sE + tid * 64;
    const int sw = tid & 31;
    #pragma unroll 8
    for (int c = 0; c < 64; ++c)
      row[c ^ sw] = ip[(size_t)c * HW];
  }
  __syncthreads();

  // phase B: GN+SiLU + enc1, 1KB-contiguous uint4 traffic
  const int o = tid & 7, pr = tid >> 3;
  const float N = 32.f * HW;
  float mean, rstd;
  gn_stats(st, b * 2 + (o >> 2), N, mean, rstd);

  #pragma unroll
  for (int i = 0; i < 8; ++i) {
    const int p = i * 32 + pr;
    const int gpx = p0 + p;
    const int y = gpx / WOUT, x = gpx - y * WOUT;
    uint4* pv = (uint4*)(buf + (((size_t)(b * HP) + y + 1) * WP + (x + 1)) * 64
                         + o * 8);
    uint4 v = *pv;
    const float* ep = sE + p * 64;
    const int sw = p & 31;
    unsigned r[4];
    #pragma unroll
    for (int k = 0; k < 4; ++k) {
      unsigned w = (k == 0) ? v.x : (k == 1) ? v.y : (k == 2) ? v.z : v.w;
      const int c0 = o * 8 + k * 2;
      float f0 = bf2f(w & 0xffffu), f1 = bf2f(w >> 16);
      float r0 = silu_f((f0 - mean) * rstd * gw[c0] + gb[c0]) + ep[c0 ^ sw];
      float r1 = silu_f((f1 - mean) * rstd * gw[c0 + 1] + gb[c0 + 1])
                 + ep[(c0 + 1) ^ sw];
      r[k] = (unsigned)f2bf(r0) | ((unsigned)f2bf(r1) << 16);
    }
    uint4 pk = {r[0], r[1], r[2], r[3]};
    *pv = pk;
  }
}

// ---- MFMA implicit-GEMM 3x3 conv, single-staged row strip -----------------
// In: padded NHWC bf16. Out: padded NHWC bf16, PRE-NORM (stats fused).

#define FE18(M) M(0) M(1) M(2) M(3) M(4) M(5) M(6) M(7) M(8) M(9) M(10) \
                M(11) M(12) M(13) M(14) M(15) M(16) M(17)

#define WDL(t) \
  v8s Wa##t = ((const v8s*)wrep)[(size_t)((t) * 4 + sub) * OCT + ocbase + lx]; \
  v8s Wb##t = ((const v8s*)wrep)[(size_t)((t) * 4 + sub) * OCT + ocbase + 16 + lx];

#define KST(t) { \
    const int col_ = xb + lx + (((t) >> 1) % 3); \
    v8s b_ = __builtin_bit_cast(v8s, sQ[((rbase + wrow + (t) / 6) * LWS + col_) * 8 + \
                                        (((((t) & 1) * 4 + sub)) ^ (col_ & 7))]); \
    a0 = __builtin_amdgcn_mfma_f32_16x16x32_bf16(Wa##t, b_, a0, 0, 0, 0); \
    a1 = __builtin_amdgcn_mfma_f32_16x16x32_bf16(Wb##t, b_, a1, 0, 0, 0); }

template<int HIN, int WIN, int WT, int NG, int RPB, int OCT, bool PSF,
         int WEU_MIN, int WEU_MAX>
__global__
__attribute__((amdgpu_flat_work_group_size(256, 256),
               amdgpu_waves_per_eu(WEU_MIN, WEU_MAX)))
void convm_k(const uint4* __restrict__ inP, const ushort* __restrict__ wrep,
             const float* __restrict__ bias, ushort* __restrict__ outP,
             float* __restrict__ stp)
{
  constexpr int HP = HIN + 2, WP = WIN + 2;
  constexpr int HPo = PSF ? (2 * HIN + 2) : (HIN + 2);
  constexpr int WPo = PSF ? (2 * WIN + 2) : (WIN + 2);
  constexpr int LH = RPB + 2, LW = WT + 2;
  constexpr int NOCB = OCT / 64;
  constexpr int LRD = (NG * 16 + 2 > LW) ? (NG * 16 + 2) : LW;
  constexpr int LWS = (LRD + 7) & ~7;      // multiple of 8: (pix&7)==(col&7)
  constexpr int NCHUNK = LH * LWS * 8;
  static_assert(NCHUNK % 256 == 0, "staging must tile evenly");
  constexpr int STK = NCHUNK / 256;
  __shared__ uint4 sQ[NCHUNK];
  __shared__ float red[4][2];

  const int tid  = threadIdx.x;
  const int lane = tid & 63;
  const int wave = tid >> 6;
  const int sub  = lane >> 4;
  const int lx   = lane & 15;
  const int wrow = wave >> 1;              // row within pair
  const int b    = blockIdx.y / NOCB;
  const int ocb  = blockIdx.y - b * NOCB;
  constexpr int NTX = WIN / WT;
  const int tx    = blockIdx.x % NTX;
  const int ych   = blockIdx.x / NTX;
  const int x0    = tx * WT;
  const int ybase = ych * RPB;
  const int ocbase = ocb * 64 + (wave & 1) * 32;

  FE18(WDL)

  const v4f bi0 = *(const v4f*)&bias[ocbase + sub * 4];
  const v4f bi1 = *(const v4f*)&bias[ocbase + 16 + sub * 4];

  // stage the whole (RPB+2)-row strip once (batched loads, one wait)
  const uint4* gbase = inP + ((size_t)(b * HP + ybase) * WP + x0) * 8;
  uint4 stg[STK];
  #pragma unroll
  for (int k = 0; k < STK; ++k) {
    int q = tid + k * 256;
    int p = q >> 3, cc = q & 7;
    int r = p / LWS, cx = p - r * LWS;
    stg[k] = gbase[((size_t)r * WP + cx) * 8 + cc];
  }
  #pragma unroll
  for (int k = 0; k < STK; ++k) {
    int q = tid + k * 256;
    int p = q >> 3, cc = q & 7;
    int cx = p - (p / LWS) * LWS;
    sQ[p * 8 + (cc ^ (cx & 7))] = stg[k];
  }
  __syncthreads();

  float sA = 0.f, qA = 0.f;

  for (int it = 0; it < RPB / 2; ++it) {
    const int rbase = it * 2;
    const int y = ybase + rbase + wrow;
    for (int xg = 0; xg < NG; ++xg) {
      const int xb = xg * 16;
      v4f a0 = bi0, a1 = bi1;
      FE18(KST)
      const int x = x0 + xb + lx;
      if ((NG * 16 == WT) || (x < WIN)) {
        if (!PSF) {
          const size_t pbase =
            (((size_t)(b * HPo) + y + 1) * WPo + (x + 1)) * 64 + (wave & 1) * 32;
          #pragma unroll
          for (int s = 0; s < 2; ++s) {
            const v4f a = s ? a1 : a0;
            uint2 pk;
            pk.x = (unsigned)f2bf(a[0]) | ((unsigned)f2bf(a[1]) << 16);
            pk.y = (unsigned)f2bf(a[2]) | ((unsigned)f2bf(a[3]) << 16);
            *(uint2*)(outP + pbase + s * 16 + sub * 4) = pk;
            #pragma unroll
            for (int j = 0; j < 4; ++j) { sA += a[j]; qA += a[j] * a[j]; }
          }
        } else {
          #pragma unroll
          for (int s = 0; s < 2; ++s) {
            const v4f a = s ? a1 : a0;
            #pragma unroll
            for (int j = 0; j < 4; ++j) {
              int oc = ocbase + s * 16 + sub * 4 + j;
              int c = oc >> 2, rr = (oc >> 1) & 1, ss = oc & 1;
              outP[(((size_t)(b * HPo) + 2 * y + rr + 1) * WPo
                    + (2 * x + ss + 1)) * 64 + c] = f2bf(a[j]);
              sA += a[j]; qA += a[j] * a[j];
            }
          }
        }
      }
    }
  }

  // GroupNorm stats (f32 accumulators, exact)
  #pragma unroll
  for (int o = 32; o >= 1; o >>= 1) {
    sA += __shfl_down(sA, o);
    qA += __shfl_down(qA, o);
  }
  if (lane == 0) { red[wave][0] = sA; red[wave][1] = qA; }
  __syncthreads();
  if (tid == 0) {
    float* basep = stp + ((blockIdx.x ^ blockIdx.y) & 7) * 64;
    if (PSF) {
      int g = ocb >> 1;
      atomicAdd(&basep[(b * 2 + g) * 2 + 0],
                red[0][0] + red[1][0] + red[2][0] + red[3][0]);
      atomicAdd(&basep[(b * 2 + g) * 2 + 1],
                red[0][1] + red[1][1] + red[2][1] + red[3][1]);
    } else {
      atomicAdd(&basep[(b * 2 + 0) * 2 + 0], red[0][0] + red[2][0]);
      atomicAdd(&basep[(b * 2 + 0) * 2 + 1], red[0][1] + red[2][1]);
      atomicAdd(&basep[(b * 2 + 1) * 2 + 0], red[1][0] + red[3][0]);
      atomicAdd(&basep[(b * 2 + 1) * 2 + 1], red[1][1] + red[3][1]);
    }
  }
}

// ---- readout, lane = (pixel, chunk-slot); 8-lane shuffle reduction --------
__global__ __launch_bounds__(256)
void readout_k(const ushort* __restrict__ Dp, const float* __restrict__ st,
               const float* __restrict__ gw, const float* __restrict__ gb,
               const float* __restrict__ rw, const float* __restrict__ rb,
               float* __restrict__ Y)
{
  int t = blockIdx.x * 256 + threadIdx.x;
  int gp = t >> 3;
  if (gp >= 16 * 25600) return;
  const int slot = t & 7;
  int b = gp / 25600, pix = gp - b * 25600;
  int y = pix / 160, x = pix - y * 160;
  const float N = 32.f * 25600.f;
  const int g = slot >> 2;
  float mean, rstd;
  gn_stats(st, b * 2 + g, N, mean, rstd);

  const uint4* p = (const uint4*)(Dp + (((size_t)(b * 162) + y + 1) * 162
                                        + (x + 1)) * 64 + slot * 8);
  uint4 v = *p;
  float a0 = 0.f, a1 = 0.f, a2 = 0.f;
  #pragma unroll
  for (int k = 0; k < 4; ++k) {
    unsigned w = (k == 0) ? v.x : (k == 1) ? v.y : (k == 2) ? v.z : v.w;
    const int c0 = slot * 8 + k * 2;
    float f0 = bf2f(w & 0xffffu), f1 = bf2f(w >> 16);
    float v0 = silu_f((f0 - mean) * rstd * gw[c0] + gb[c0]);
    float v1 = silu_f((f1 - mean) * rstd * gw[c0 + 1] + gb[c0 + 1]);
    a0 = fmaf(v0, rw[c0], a0);       a0 = fmaf(v1, rw[c0 + 1], a0);
    a1 = fmaf(v0, rw[64 + c0], a1);  a1 = fmaf(v1, rw[64 + c0 + 1], a1);
    a2 = fmaf(v0, rw[128 + c0], a2); a2 = fmaf(v1, rw[128 + c0 + 1], a2);
  }
  #pragma unroll
  for (int m = 1; m < 8; m <<= 1) {
    a0 += __shfl_xor(a0, m);
    a1 += __shfl_xor(a1, m);
    a2 += __shfl_xor(a2, m);
  }
  if (slot == 0) {
    Y[(size_t)(b * 3 + 0) * 25600 + pix] = a0 + rb[0];
    Y[(size_t)(b * 3 + 1) * 25600 + pix] = a1 + rb[1];
    Y[(size_t)(b * 3 + 2) * 25600 + pix] = a2 + rb[2];
  }
}

// ---- feamap: argx = conv(Y, fw, stride 4)/16, first 3 channels ------------
__global__ void feamap_k(const float* __restrict__ Y, const float* __restrict__ fw,
                         float* __restrict__ argx)
{
  int idx = blockIdx.x * 256 + threadIdx.x;
  if (idx >= 16 * 3 * 1600) return;
  int b  = idx / (3 * 1600);
  int o  = (idx / 1600) % 3;
  int ij = idx % 1600;
  int i = ij / 40, j = ij - i * 40;
  float s = 0.f;
  #pragma unroll
  for (int c = 0; c < 3; ++c)
    #pragma unroll
    for (int u = 0; u < 4; ++u)
      #pragma unroll
      for (int v = 0; v < 4; ++v)
        s += Y[((size_t)(b * 3 + c) * 160 + (4 * i + u)) * 160 + (4 * j + v)]
             * fw[((o * 3 + c) * 4 + u) * 4 + v];
  argx[idx] = s * (1.f / 16.f);
}

__global__ void nz_k(const float* __restrict__ attn, float* __restrict__ nzinv) {
  int idx = blockIdx.x * 256 + threadIdx.x;
  if (idx >= 16 * 3 * 256) return;
  const float* p = attn + (size_t)idx * 16;
  int c = 0;
  #pragma unroll
  for (int k = 0; k < 16; ++k) c += (p[k] != 0.f);
  nzinv[idx] = 1.f / ((float)c + 1e-5f);
}

__global__ void final_k(const float* __restrict__ Y, const float* __restrict__ attn,
                        const float* __restrict__ nzinv, const float* __restrict__ argx,
                        float* __restrict__ out)
{
  int idx = blockIdx.x * 256 + threadIdx.x;
  if (idx >= 16 * 3 * 25600) return;
  int bc  = idx / 25600;
  int pix = idx - bc * 25600;
  int y = pix / 160, x = pix - y * 160;
  int l  = (y / 10) * 16 + (x / 10);
  int pi = y % 10,  pj = x % 10;
  const float* ar = attn + ((size_t)bc * 256 + l) * 16;
  const float* ax = argx + (size_t)bc * 1600;
  float inv = nzinv[bc * 256 + l];
  float corr = 0.f;
  #pragma unroll
  for (int k = 0; k < 16; ++k)
    corr += ar[k] * ax[((k >> 2) * 10 + pi) * 40 + ((k & 3) * 10 + pj)];
  float yv = Y[idx];
  out[idx] = yv * (1.f + corr * inv);
}

// ---------------------------------------------------------------------------
extern "C" void kernel_launch(void* const* d_in, const int* in_sizes, int n_in,
                              void* d_out, int out_size, void* d_ws, size_t ws_size,
                              hipStream_t stream)
{
  const float* attn = (const float*)d_in[0];
  const float* hid  = (const float*)d_in[1];
  const float* enc1 = (const float*)d_in[2];
  const float* d0w  = (const float*)d_in[3];
  const float* d0b  = (const float*)d_in[4];
  const float* d0gw = (const float*)d_in[5];
  const float* d0gb = (const float*)d_in[6];
  const float* d1w  = (const float*)d_in[7];
  const float* d1b  = (const float*)d_in[8];
  const float* d1gw = (const float*)d_in[9];
  const float* d1gb = (const float*)d_in[10];
  const float* d2w  = (const float*)d_in[11];
  const float* d2b  = (const float*)d_in[12];
  const float* d2gw = (const float*)d_in[13];
  const float* d2gb = (const float*)d_in[14];
  const float* d3w  = (const float*)d_in[15];
  const float* d3b  = (const float*)d_in[16];
  const float* d3gw = (const float*)d_in[17];
  const float* d3gb = (const float*)d_in[18];
  const float* rw   = (const float*)d_in[19];
  const float* rb   = (const float*)d_in[20];
  const float* fw   = (const float*)d_in[21];

  float* ws = (float*)d_ws;
  size_t o = 0;
  float* bufA  = ws + o; o += (size_t)16 * 64 * 80 * 80;         // Y+argx+nzv
  float* Abff  = ws + o; o += (size_t)16 * 82 * 82 * 64 / 2;     // Abf
  float* Bbff  = ws + o; o += (size_t)16 * 82 * 82 * 64 / 2;     // Bbf
  float* Cbff  = ws + o; o += (size_t)16 * 162 * 162 * 64 / 2;   // Cbf
  float* Dbff  = ws + o; o += (size_t)16 * 162 * 162 * 64 / 2;   // Dbf
  float* hidPf = ws + o; o += (size_t)16 * 42 * 42 * 64 / 2;     // hidP
  float* st    = ws + o; o += 4 * 512;                           // slotted stats
  float* w0f   = ws + o; o += (size_t)72 * 256 * 8 / 2;
  float* w1f   = ws + o; o += (size_t)72 * 64 * 8 / 2;
  float* w2f   = ws + o; o += (size_t)72 * 256 * 8 / 2;
  float* w3f   = ws + o; o += (size_t)72 * 64 * 8 / 2;

  ushort* Abf  = (ushort*)Abff;
  ushort* Bbf  = (ushort*)Bbff;
  ushort* Cbf  = (ushort*)Cbff;
  ushort* Dbf  = (ushort*)Dbff;
  ushort* hidP = (ushort*)hidPf;
  float*  Y    = bufA;
  float*  argx = bufA + (size_t)16 * 3 * 25600;
  float*  nzv  = argx + (size_t)16 * 3 * 1600;
  ushort* wr0  = (ushort*)w0f;
  ushort* wr1  = (ushort*)w1f;
  ushort* wr2  = (ushort*)w2f;
  ushort* wr3  = (ushort*)w3f;

  zero_k<<<8, 256, 0, stream>>>(st, 4 * 512);

  repackw_k<256><<<(256 * 576 + 255) / 256, 256, 0, stream>>>(d0w, wr0);
  repackw_k<64><<<(64 * 576 + 255) / 256, 256, 0, stream>>>(d1w, wr1);
  repackw_k<256><<<(256 * 576 + 255) / 256, 256, 0, stream>>>(d2w, wr2);
  repackw_k<64><<<(64 * 576 + 255) / 256, 256, 0, stream>>>(d3w, wr3);

  // borders (zeroed every call; convs write interiors only)
  border_k<42, 42><<<(16 * 42 * 42 + 255) / 256, 256, 0, stream>>>(hidP);
  border_k<82, 82><<<(16 * 82 * 82 + 255) / 256, 256, 0, stream>>>(Abf);
  border_k<82, 82><<<(16 * 82 * 82 + 255) / 256, 256, 0, stream>>>(Bbf);
  border_k<162, 162><<<(16 * 162 * 162 + 255) / 256, 256, 0, stream>>>(Cbf);

  // pad hid -> hidP (NHWC bf16)
  pad_k<1600, 40><<<16 * 7, 256, 0, stream>>>(hid, hidP);

  // stage 0: conv(hidP)+PS -> Abf (pre-norm), stats st0
  convm_k<40, 40, 40, 3, 10, 256, true, 1, 1>
    <<<dim3(4, 16 * 4), 256, 0, stream>>>((const uint4*)hidP, wr0, d0b, Abf,
                                          st + 0 * 512);
  // actn1: in-place GN+SiLU on Abf
  actn_k<80, 80><<<16 * 6400 * 8 / 256, 256, 0, stream>>>(
      Abf, st + 0 * 512, d0gw, d0gb);

  // stage 1: conv(Abf) -> Bbf (pre-norm), stats st1
  convm_k<80, 80, 16, 1, 10, 64, false, 2, 2>
    <<<dim3(40, 16), 256, 0, stream>>>((const uint4*)Abf, wr1, d1b, Bbf,
                                       st + 1 * 512);
  // actn2: in-place GN+SiLU on Bbf
  actn_k<80, 80><<<16 * 6400 * 8 / 256, 256, 0, stream>>>(
      Bbf, st + 1 * 512, d1gw, d1gb);

  // stage 2: conv(Bbf)+PS -> Cbf (pre-norm), stats st2
  convm_k<80, 80, 16, 1, 10, 256, true, 2, 2>
    <<<dim3(40, 16 * 4), 256, 0, stream>>>((const uint4*)Bbf, wr2, d2b, Cbf,
                                           st + 2 * 512);
  // actn3: in-place GN+SiLU + enc1 (LDS-staged) on Cbf
  actne_k<<<16 * 100, 256, 0, stream>>>(Cbf, st + 2 * 512, d2gw, d2gb, enc1);

  // stage 3: conv(Cbf) -> Dbf (pre-norm), stats st3
  convm_k<160, 160, 16, 1, 10, 64, false, 2, 2>
    <<<dim3(160, 16), 256, 0, stream>>>((const uint4*)Cbf, wr3, d3b, Dbf,
                                        st + 3 * 512);

  // readout: Y = 1x1conv(GN_SiLU(Dbf))
  readout_k<<<16 * 25600 * 8 / 256, 256, 0, stream>>>(Dbf, st + 3 * 512,
      d3gw, d3gb, rw, rb, Y);

  feamap_k<<<(16 * 3 * 1600 + 255) / 256, 256, 0, stream>>>(Y, fw, argx);
  nz_k<<<(16 * 3 * 256 + 255) / 256, 256, 0, stream>>>(attn, nzv);
  final_k<<<(16 * 3 * 25600 + 255) / 256, 256, 0, stream>>>(Y, attn, nzv, argx,
      (float*)d_out);
}

// Round 15
// 301.097 us; speedup vs baseline: 1.1273x; 1.0203x over previous
//
#include <hip/hip_runtime.h>

// ---------------------------------------------------------------------------
// SimVP Decoder, round 15: R14 + conv occupancy uncap + 3-deep ds_read batch.
// R14 post-mortem: waves_per_eu(2,2) MAX capped convs at 2 blocks/CU, and
// VGPR=108 (weights streamed) left no room to hoist B-frags -> serial
// ds_read(120cy)->MFMA per K-step = 72us stage-3 conv (arithmetic matches).
// Now: waves_per_eu(2,4) (4 blocks/CU fit: VGPR 108<=128, LDS 37.4KBx4<160KB)
// and K-steps grouped {3x ds_read -> 6x MFMA} via named temps.
// Everything else identical to R14 (passed).
// ---------------------------------------------------------------------------

#define DEVFN static __device__ __forceinline__

typedef short v8s __attribute__((ext_vector_type(8)));
typedef float v4f __attribute__((ext_vector_type(4)));

DEVFN float silu_f(float t) { return t / (1.f + __expf(-t)); }

DEVFN ushort f2bf(float x) {
  union { float f; unsigned u; } t; t.f = x;
  unsigned r = t.u + 0x7FFFu + ((t.u >> 16) & 1u);
  return (ushort)(r >> 16);
}

DEVFN float bf2f(unsigned u) {
  union { unsigned i; float f; } t; t.i = u << 16; return t.f;
}

__global__ void zero_k(float* __restrict__ p, int n) {
  int i = blockIdx.x * 256 + threadIdx.x;
  if (i < n) p[i] = 0.f;
}

// ---- weight repack: [OC][64][3][3] f32 -> bf16 [kc=tap*8+ic/8][OC][8] -----
template<int OC>
__global__ void repackw_k(const float* __restrict__ src, ushort* __restrict__ dst) {
  int i = blockIdx.x * 256 + threadIdx.x;
  if (i >= OC * 576) return;
  int oc = i / 576, r = i - oc * 576;      // r = ic*9 + tap
  int ic = r / 9, tap = r - ic * 9;
  int kc = tap * 8 + (ic >> 3), j = ic & 7;
  dst[((size_t)kc * OC + oc) * 8 + j] = f2bf(src[i]);
}

// ---- zero the 1-px border of a padded NHWC bf16 buffer --------------------
template<int HP, int WP>
__global__ void border_k(ushort* __restrict__ outP) {
  int idx = blockIdx.x * 256 + threadIdx.x;
  if (idx >= 16 * HP * WP) return;
  int p = idx % (HP * WP);
  int y = p / WP, x = p - y * WP;
  if (y == 0 || y == HP - 1 || x == 0 || x == WP - 1) {
    uint4 z = {0u, 0u, 0u, 0u};
    uint4* dst = (uint4*)(outP + (size_t)idx * 64);
    #pragma unroll
    for (int k = 0; k < 8; ++k) dst[k] = z;
  }
}

// ---- slot-summed GN stats -> (mean, rstd) ---------------------------------
DEVFN void gn_stats(const float* __restrict__ st, int bg, float N,
                    float& mean, float& rstd) {
  float s = 0.f, q = 0.f;
  #pragma unroll
  for (int sl = 0; sl < 8; ++sl) {
    s += st[sl * 64 + bg * 2 + 0];
    q += st[sl * 64 + bg * 2 + 1];
  }
  float m = s / N;
  mean = m;
  rstd = rsqrtf(q / N - m * m + 1e-5f);
}

// ---- pad/transpose: NCHW f32 -> padded NHWC bf16 (raw copy, for hid) ------
template<int HW_TOT, int WOUT>
__global__ __launch_bounds__(256)
void pad_k(const float* __restrict__ in, ushort* __restrict__ outP)
{
  constexpr int HOUT = HW_TOT / WOUT;
  constexpr int WP = WOUT + 2, HP = HOUT + 2;
  __shared__ uint4 sT[256 * 8];
  const int tid = threadIdx.x;
  constexpr int NBLK = (HW_TOT + 255) / 256;
  const int b  = blockIdx.x / NBLK;
  const int p0 = (blockIdx.x - b * NBLK) * 256;
  const int px = p0 + tid;

  if (px < HW_TOT) {
    const float* ip = in + (size_t)b * 64 * HW_TOT + px;
    #pragma unroll 2
    for (int cc = 0; cc < 8; ++cc) {
      unsigned w[4];
      #pragma unroll
      for (int jp = 0; jp < 4; ++jp) {
        float v0 = ip[(size_t)(cc * 8 + jp * 2) * HW_TOT];
        float v1 = ip[(size_t)(cc * 8 + jp * 2 + 1) * HW_TOT];
        w[jp] = (unsigned)f2bf(v0) | ((unsigned)f2bf(v1) << 16);
      }
      uint4 pk = {w[0], w[1], w[2], w[3]};
      sT[tid * 8 + (cc ^ (tid & 7))] = pk;
    }
  }
  __syncthreads();
  const int o = tid & 7, pr = tid >> 3;
  #pragma unroll
  for (int i = 0; i < 8; ++i) {
    int p = i * 32 + pr;
    int gpx = p0 + p;
    if (gpx < HW_TOT) {
      int y = gpx / WOUT, x = gpx - y * WOUT;
      uint4 val = sT[p * 8 + (o ^ (p & 7))];
      *(uint4*)(outP + (((size_t)(b * HP) + y + 1) * WP + (x + 1)) * 64 + o * 8) = val;
    }
  }
}

// ---- in-place GN+SiLU (no addend), lane = (pixel, chunk-slot) -------------
template<int HOUT, int WOUT>
__global__ __launch_bounds__(256)
void actn_k(ushort* __restrict__ buf, const float* __restrict__ st,
            const float* __restrict__ gw, const float* __restrict__ gb)
{
  constexpr int HW = HOUT * WOUT;
  constexpr int WP = WOUT + 2, HP = HOUT + 2;
  int t = blockIdx.x * 256 + threadIdx.x;
  int gp = t >> 3;
  if (gp >= 16 * HW) return;
  const int slot = t & 7;
  int b = gp / HW, pix = gp - b * HW;
  int y = pix / WOUT, x = pix - y * WOUT;

  const float N = 32.f * HW;
  const int g = slot >> 2;
  float mean, rstd;
  gn_stats(st, b * 2 + g, N, mean, rstd);

  uint4* pv = (uint4*)(buf + (((size_t)(b * HP) + y + 1) * WP + (x + 1)) * 64
                       + slot * 8);
  uint4 v = *pv;
  unsigned r[4];
  #pragma unroll
  for (int k = 0; k < 4; ++k) {
    unsigned w = (k == 0) ? v.x : (k == 1) ? v.y : (k == 2) ? v.z : v.w;
    const int c0 = slot * 8 + k * 2;
    float f0 = bf2f(w & 0xffffu), f1 = bf2f(w >> 16);
    float r0 = silu_f((f0 - mean) * rstd * gw[c0] + gb[c0]);
    float r1 = silu_f((f1 - mean) * rstd * gw[c0 + 1] + gb[c0 + 1]);
    r[k] = (unsigned)f2bf(r0) | ((unsigned)f2bf(r1) << 16);
  }
  uint4 pk = {r[0], r[1], r[2], r[3]};
  *pv = pk;
}

// ---- in-place GN+SiLU + enc1 via f32 LDS transpose (for actn3) ------------
__global__ __launch_bounds__(256)
void actne_k(ushort* __restrict__ buf, const float* __restrict__ st,
             const float* __restrict__ gw, const float* __restrict__ gb,
             const float* __restrict__ addsrc)
{
  constexpr int HW = 25600, WOUT = 160, WP = 162, HP = 162;
  __shared__ float sE[256 * 64];           // 64 KB
  const int tid = threadIdx.x;
  const int b   = blockIdx.x / 100;
  const int p0  = (blockIdx.x - b * 100) * 256;

  {
    const float* ip = addsrc + (size_t)b * 64 * HW + p0 + tid;
    float* row = sE + tid * 64;
    const int sw = tid & 31;
    #pragma unroll 8
    for (int c = 0; c < 64; ++c)
      row[c ^ sw] = ip[(size_t)c * HW];
  }
  __syncthreads();

  const int o = tid & 7, pr = tid >> 3;
  const float N = 32.f * HW;
  float mean, rstd;
  gn_stats(st, b * 2 + (o >> 2), N, mean, rstd);

  #pragma unroll
  for (int i = 0; i < 8; ++i) {
    const int p = i * 32 + pr;
    const int gpx = p0 + p;
    const int y = gpx / WOUT, x = gpx - y * WOUT;
    uint4* pv = (uint4*)(buf + (((size_t)(b * HP) + y + 1) * WP + (x + 1)) * 64
                         + o * 8);
    uint4 v = *pv;
    const float* ep = sE + p * 64;
    const int sw = p & 31;
    unsigned r[4];
    #pragma unroll
    for (int k = 0; k < 4; ++k) {
      unsigned w = (k == 0) ? v.x : (k == 1) ? v.y : (k == 2) ? v.z : v.w;
      const int c0 = o * 8 + k * 2;
      float f0 = bf2f(w & 0xffffu), f1 = bf2f(w >> 16);
      float r0 = silu_f((f0 - mean) * rstd * gw[c0] + gb[c0]) + ep[c0 ^ sw];
      float r1 = silu_f((f1 - mean) * rstd * gw[c0 + 1] + gb[c0 + 1])
                 + ep[(c0 + 1) ^ sw];
      r[k] = (unsigned)f2bf(r0) | ((unsigned)f2bf(r1) << 16);
    }
    uint4 pk = {r[0], r[1], r[2], r[3]};
    *pv = pk;
  }
}

// ---- MFMA implicit-GEMM 3x3 conv, single-staged row strip -----------------
// In: padded NHWC bf16. Out: padded NHWC bf16, PRE-NORM (stats fused).
// K-steps grouped {3 ds_read -> 6 MFMA} for lgkmcnt batching.

#define FE18(M) M(0) M(1) M(2) M(3) M(4) M(5) M(6) M(7) M(8) M(9) M(10) \
                M(11) M(12) M(13) M(14) M(15) M(16) M(17)

#define WDL(t) \
  v8s Wa##t = ((const v8s*)wrep)[(size_t)((t) * 4 + sub) * OCT + ocbase + lx]; \
  v8s Wb##t = ((const v8s*)wrep)[(size_t)((t) * 4 + sub) * OCT + ocbase + 16 + lx];

// B-fragment read expression: step t (dy=t/6, dx=(t>>1)%3, half=t&1)
#define BRDX(t) __builtin_bit_cast(v8s, sQ[ \
    ((rbase + wrow + (t) / 6) * LWS + (xb + lx + (((t) >> 1) % 3))) * 8 + \
    (((((t) & 1) * 4 + sub)) ^ ((xb + lx + (((t) >> 1) % 3)) & 7))])

#define KG3(t0, t1, t2) { \
    v8s bA_ = BRDX(t0); v8s bB_ = BRDX(t1); v8s bC_ = BRDX(t2); \
    a0 = __builtin_amdgcn_mfma_f32_16x16x32_bf16(Wa##t0, bA_, a0, 0, 0, 0); \
    a1 = __builtin_amdgcn_mfma_f32_16x16x32_bf16(Wb##t0, bA_, a1, 0, 0, 0); \
    a0 = __builtin_amdgcn_mfma_f32_16x16x32_bf16(Wa##t1, bB_, a0, 0, 0, 0); \
    a1 = __builtin_amdgcn_mfma_f32_16x16x32_bf16(Wb##t1, bB_, a1, 0, 0, 0); \
    a0 = __builtin_amdgcn_mfma_f32_16x16x32_bf16(Wa##t2, bC_, a0, 0, 0, 0); \
    a1 = __builtin_amdgcn_mfma_f32_16x16x32_bf16(Wb##t2, bC_, a1, 0, 0, 0); }

template<int HIN, int WIN, int WT, int NG, int RPB, int OCT, bool PSF,
         int WEU_MIN, int WEU_MAX>
__global__
__attribute__((amdgpu_flat_work_group_size(256, 256),
               amdgpu_waves_per_eu(WEU_MIN, WEU_MAX)))
void convm_k(const uint4* __restrict__ inP, const ushort* __restrict__ wrep,
             const float* __restrict__ bias, ushort* __restrict__ outP,
             float* __restrict__ stp)
{
  constexpr int HP = HIN + 2, WP = WIN + 2;
  constexpr int HPo = PSF ? (2 * HIN + 2) : (HIN + 2);
  constexpr int WPo = PSF ? (2 * WIN + 2) : (WIN + 2);
  constexpr int LH = RPB + 2, LW = WT + 2;
  constexpr int NOCB = OCT / 64;
  constexpr int LRD = (NG * 16 + 2 > LW) ? (NG * 16 + 2) : LW;
  constexpr int LWS = (LRD + 7) & ~7;      // multiple of 8: (pix&7)==(col&7)
  constexpr int NCHUNK = LH * LWS * 8;
  static_assert(NCHUNK % 256 == 0, "staging must tile evenly");
  constexpr int STK = NCHUNK / 256;
  __shared__ uint4 sQ[NCHUNK];
  __shared__ float red[4][2];

  const int tid  = threadIdx.x;
  const int lane = tid & 63;
  const int wave = tid >> 6;
  const int sub  = lane >> 4;
  const int lx   = lane & 15;
  const int wrow = wave >> 1;              // row within pair
  const int b    = blockIdx.y / NOCB;
  const int ocb  = blockIdx.y - b * NOCB;
  constexpr int NTX = WIN / WT;
  const int tx    = blockIdx.x % NTX;
  const int ych   = blockIdx.x / NTX;
  const int x0    = tx * WT;
  const int ybase = ych * RPB;
  const int ocbase = ocb * 64 + (wave & 1) * 32;

  FE18(WDL)

  const v4f bi0 = *(const v4f*)&bias[ocbase + sub * 4];
  const v4f bi1 = *(const v4f*)&bias[ocbase + 16 + sub * 4];

  // stage the whole (RPB+2)-row strip once (batched loads, one wait)
  const uint4* gbase = inP + ((size_t)(b * HP + ybase) * WP + x0) * 8;
  uint4 stg[STK];
  #pragma unroll
  for (int k = 0; k < STK; ++k) {
    int q = tid + k * 256;
    int p = q >> 3, cc = q & 7;
    int r = p / LWS, cx = p - r * LWS;
    stg[k] = gbase[((size_t)r * WP + cx) * 8 + cc];
  }
  #pragma unroll
  for (int k = 0; k < STK; ++k) {
    int q = tid + k * 256;
    int p = q >> 3, cc = q & 7;
    int cx = p - (p / LWS) * LWS;
    sQ[p * 8 + (cc ^ (cx & 7))] = stg[k];
  }
  __syncthreads();

  float sA = 0.f, qA = 0.f;

  for (int it = 0; it < RPB / 2; ++it) {
    const int rbase = it * 2;
    const int y = ybase + rbase + wrow;
    for (int xg = 0; xg < NG; ++xg) {
      const int xb = xg * 16;
      v4f a0 = bi0, a1 = bi1;
      KG3(0, 1, 2)  KG3(3, 4, 5)  KG3(6, 7, 8)
      KG3(9, 10, 11) KG3(12, 13, 14) KG3(15, 16, 17)
      const int x = x0 + xb + lx;
      if ((NG * 16 == WT) || (x < WIN)) {
        if (!PSF) {
          const size_t pbase =
            (((size_t)(b * HPo) + y + 1) * WPo + (x + 1)) * 64 + (wave & 1) * 32;
          #pragma unroll
          for (int s = 0; s < 2; ++s) {
            const v4f a = s ? a1 : a0;
            uint2 pk;
            pk.x = (unsigned)f2bf(a[0]) | ((unsigned)f2bf(a[1]) << 16);
            pk.y = (unsigned)f2bf(a[2]) | ((unsigned)f2bf(a[3]) << 16);
            *(uint2*)(outP + pbase + s * 16 + sub * 4) = pk;
            #pragma unroll
            for (int j = 0; j < 4; ++j) { sA += a[j]; qA += a[j] * a[j]; }
          }
        } else {
          #pragma unroll
          for (int s = 0; s < 2; ++s) {
            const v4f a = s ? a1 : a0;
            #pragma unroll
            for (int j = 0; j < 4; ++j) {
              int oc = ocbase + s * 16 + sub * 4 + j;
              int c = oc >> 2, rr = (oc >> 1) & 1, ss = oc & 1;
              outP[(((size_t)(b * HPo) + 2 * y + rr + 1) * WPo
                    + (2 * x + ss + 1)) * 64 + c] = f2bf(a[j]);
              sA += a[j]; qA += a[j] * a[j];
            }
          }
        }
      }
    }
  }

  // GroupNorm stats (f32 accumulators, exact)
  #pragma unroll
  for (int o = 32; o >= 1; o >>= 1) {
    sA += __shfl_down(sA, o);
    qA += __shfl_down(qA, o);
  }
  if (lane == 0) { red[wave][0] = sA; red[wave][1] = qA; }
  __syncthreads();
  if (tid == 0) {
    float* basep = stp + ((blockIdx.x ^ blockIdx.y) & 7) * 64;
    if (PSF) {
      int g = ocb >> 1;
      atomicAdd(&basep[(b * 2 + g) * 2 + 0],
                red[0][0] + red[1][0] + red[2][0] + red[3][0]);
      atomicAdd(&basep[(b * 2 + g) * 2 + 1],
                red[0][1] + red[1][1] + red[2][1] + red[3][1]);
    } else {
      atomicAdd(&basep[(b * 2 + 0) * 2 + 0], red[0][0] + red[2][0]);
      atomicAdd(&basep[(b * 2 + 0) * 2 + 1], red[0][1] + red[2][1]);
      atomicAdd(&basep[(b * 2 + 1) * 2 + 0], red[1][0] + red[3][0]);
      atomicAdd(&basep[(b * 2 + 1) * 2 + 1], red[1][1] + red[3][1]);
    }
  }
}

// ---- readout, lane = (pixel, chunk-slot); 8-lane shuffle reduction --------
__global__ __launch_bounds__(256)
void readout_k(const ushort* __restrict__ Dp, const float* __restrict__ st,
               const float* __restrict__ gw, const float* __restrict__ gb,
               const float* __restrict__ rw, const float* __restrict__ rb,
               float* __restrict__ Y)
{
  int t = blockIdx.x * 256 + threadIdx.x;
  int gp = t >> 3;
  if (gp >= 16 * 25600) return;
  const int slot = t & 7;
  int b = gp / 25600, pix = gp - b * 25600;
  int y = pix / 160, x = pix - y * 160;
  const float N = 32.f * 25600.f;
  const int g = slot >> 2;
  float mean, rstd;
  gn_stats(st, b * 2 + g, N, mean, rstd);

  const uint4* p = (const uint4*)(Dp + (((size_t)(b * 162) + y + 1) * 162
                                        + (x + 1)) * 64 + slot * 8);
  uint4 v = *p;
  float a0 = 0.f, a1 = 0.f, a2 = 0.f;
  #pragma unroll
  for (int k = 0; k < 4; ++k) {
    unsigned w = (k == 0) ? v.x : (k == 1) ? v.y : (k == 2) ? v.z : v.w;
    const int c0 = slot * 8 + k * 2;
    float f0 = bf2f(w & 0xffffu), f1 = bf2f(w >> 16);
    float v0 = silu_f((f0 - mean) * rstd * gw[c0] + gb[c0]);
    float v1 = silu_f((f1 - mean) * rstd * gw[c0 + 1] + gb[c0 + 1]);
    a0 = fmaf(v0, rw[c0], a0);       a0 = fmaf(v1, rw[c0 + 1], a0);
    a1 = fmaf(v0, rw[64 + c0], a1);  a1 = fmaf(v1, rw[64 + c0 + 1], a1);
    a2 = fmaf(v0, rw[128 + c0], a2); a2 = fmaf(v1, rw[128 + c0 + 1], a2);
  }
  #pragma unroll
  for (int m = 1; m < 8; m <<= 1) {
    a0 += __shfl_xor(a0, m);
    a1 += __shfl_xor(a1, m);
    a2 += __shfl_xor(a2, m);
  }
  if (slot == 0) {
    Y[(size_t)(b * 3 + 0) * 25600 + pix] = a0 + rb[0];
    Y[(size_t)(b * 3 + 1) * 25600 + pix] = a1 + rb[1];
    Y[(size_t)(b * 3 + 2) * 25600 + pix] = a2 + rb[2];
  }
}

// ---- feamap: argx = conv(Y, fw, stride 4)/16, first 3 channels ------------
__global__ void feamap_k(const float* __restrict__ Y, const float* __restrict__ fw,
                         float* __restrict__ argx)
{
  int idx = blockIdx.x * 256 + threadIdx.x;
  if (idx >= 16 * 3 * 1600) return;
  int b  = idx / (3 * 1600);
  int o  = (idx / 1600) % 3;
  int ij = idx % 1600;
  int i = ij / 40, j = ij - i * 40;
  float s = 0.f;
  #pragma unroll
  for (int c = 0; c < 3; ++c)
    #pragma unroll
    for (int u = 0; u < 4; ++u)
      #pragma unroll
      for (int v = 0; v < 4; ++v)
        s += Y[((size_t)(b * 3 + c) * 160 + (4 * i + u)) * 160 + (4 * j + v)]
             * fw[((o * 3 + c) * 4 + u) * 4 + v];
  argx[idx] = s * (1.f / 16.f);
}

__global__ void nz_k(const float* __restrict__ attn, float* __restrict__ nzinv) {
  int idx = blockIdx.x * 256 + threadIdx.x;
  if (idx >= 16 * 3 * 256) return;
  const float* p = attn + (size_t)idx * 16;
  int c = 0;
  #pragma unroll
  for (int k = 0; k < 16; ++k) c += (p[k] != 0.f);
  nzinv[idx] = 1.f / ((float)c + 1e-5f);
}

__global__ void final_k(const float* __restrict__ Y, const float* __restrict__ attn,
                        const float* __restrict__ nzinv, const float* __restrict__ argx,
                        float* __restrict__ out)
{
  int idx = blockIdx.x * 256 + threadIdx.x;
  if (idx >= 16 * 3 * 25600) return;
  int bc  = idx / 25600;
  int pix = idx - bc * 25600;
  int y = pix / 160, x = pix - y * 160;
  int l  = (y / 10) * 16 + (x / 10);
  int pi = y % 10,  pj = x % 10;
  const float* ar = attn + ((size_t)bc * 256 + l) * 16;
  const float* ax = argx + (size_t)bc * 1600;
  float inv = nzinv[bc * 256 + l];
  float corr = 0.f;
  #pragma unroll
  for (int k = 0; k < 16; ++k)
    corr += ar[k] * ax[((k >> 2) * 10 + pi) * 40 + ((k & 3) * 10 + pj)];
  float yv = Y[idx];
  out[idx] = yv * (1.f + corr * inv);
}

// ---------------------------------------------------------------------------
extern "C" void kernel_launch(void* const* d_in, const int* in_sizes, int n_in,
                              void* d_out, int out_size, void* d_ws, size_t ws_size,
                              hipStream_t stream)
{
  const float* attn = (const float*)d_in[0];
  const float* hid  = (const float*)d_in[1];
  const float* enc1 = (const float*)d_in[2];
  const float* d0w  = (const float*)d_in[3];
  const float* d0b  = (const float*)d_in[4];
  const float* d0gw = (const float*)d_in[5];
  const float* d0gb = (const float*)d_in[6];
  const float* d1w  = (const float*)d_in[7];
  const float* d1b  = (const float*)d_in[8];
  const float* d1gw = (const float*)d_in[9];
  const float* d1gb = (const float*)d_in[10];
  const float* d2w  = (const float*)d_in[11];
  const float* d2b  = (const float*)d_in[12];
  const float* d2gw = (const float*)d_in[13];
  const float* d2gb = (const float*)d_in[14];
  const float* d3w  = (const float*)d_in[15];
  const float* d3b  = (const float*)d_in[16];
  const float* d3gw = (const float*)d_in[17];
  const float* d3gb = (const float*)d_in[18];
  const float* rw   = (const float*)d_in[19];
  const float* rb   = (const float*)d_in[20];
  const float* fw   = (const float*)d_in[21];

  float* ws = (float*)d_ws;
  size_t o = 0;
  float* bufA  = ws + o; o += (size_t)16 * 64 * 80 * 80;         // Y+argx+nzv
  float* Abff  = ws + o; o += (size_t)16 * 82 * 82 * 64 / 2;     // Abf
  float* Bbff  = ws + o; o += (size_t)16 * 82 * 82 * 64 / 2;     // Bbf
  float* Cbff  = ws + o; o += (size_t)16 * 162 * 162 * 64 / 2;   // Cbf
  float* Dbff  = ws + o; o += (size_t)16 * 162 * 162 * 64 / 2;   // Dbf
  float* hidPf = ws + o; o += (size_t)16 * 42 * 42 * 64 / 2;     // hidP
  float* st    = ws + o; o += 4 * 512;                           // slotted stats
  float* w0f   = ws + o; o += (size_t)72 * 256 * 8 / 2;
  float* w1f   = ws + o; o += (size_t)72 * 64 * 8 / 2;
  float* w2f   = ws + o; o += (size_t)72 * 256 * 8 / 2;
  float* w3f   = ws + o; o += (size_t)72 * 64 * 8 / 2;

  ushort* Abf  = (ushort*)Abff;
  ushort* Bbf  = (ushort*)Bbff;
  ushort* Cbf  = (ushort*)Cbff;
  ushort* Dbf  = (ushort*)Dbff;
  ushort* hidP = (ushort*)hidPf;
  float*  Y    = bufA;
  float*  argx = bufA + (size_t)16 * 3 * 25600;
  float*  nzv  = argx + (size_t)16 * 3 * 1600;
  ushort* wr0  = (ushort*)w0f;
  ushort* wr1  = (ushort*)w1f;
  ushort* wr2  = (ushort*)w2f;
  ushort* wr3  = (ushort*)w3f;

  zero_k<<<8, 256, 0, stream>>>(st, 4 * 512);

  repackw_k<256><<<(256 * 576 + 255) / 256, 256, 0, stream>>>(d0w, wr0);
  repackw_k<64><<<(64 * 576 + 255) / 256, 256, 0, stream>>>(d1w, wr1);
  repackw_k<256><<<(256 * 576 + 255) / 256, 256, 0, stream>>>(d2w, wr2);
  repackw_k<64><<<(64 * 576 + 255) / 256, 256, 0, stream>>>(d3w, wr3);

  // borders (zeroed every call; convs write interiors only)
  border_k<42, 42><<<(16 * 42 * 42 + 255) / 256, 256, 0, stream>>>(hidP);
  border_k<82, 82><<<(16 * 82 * 82 + 255) / 256, 256, 0, stream>>>(Abf);
  border_k<82, 82><<<(16 * 82 * 82 + 255) / 256, 256, 0, stream>>>(Bbf);
  border_k<162, 162><<<(16 * 162 * 162 + 255) / 256, 256, 0, stream>>>(Cbf);

  // pad hid -> hidP (NHWC bf16)
  pad_k<1600, 40><<<16 * 7, 256, 0, stream>>>(hid, hidP);

  // stage 0: conv(hidP)+PS -> Abf (pre-norm), stats st0
  convm_k<40, 40, 40, 3, 10, 256, true, 1, 1>
    <<<dim3(4, 16 * 4), 256, 0, stream>>>((const uint4*)hidP, wr0, d0b, Abf,
                                          st + 0 * 512);
  // actn1: in-place GN+SiLU on Abf
  actn_k<80, 80><<<16 * 6400 * 8 / 256, 256, 0, stream>>>(
      Abf, st + 0 * 512, d0gw, d0gb);

  // stage 1: conv(Abf) -> Bbf (pre-norm), stats st1
  convm_k<80, 80, 16, 1, 10, 64, false, 2, 4>
    <<<dim3(40, 16), 256, 0, stream>>>((const uint4*)Abf, wr1, d1b, Bbf,
                                       st + 1 * 512);
  // actn2: in-place GN+SiLU on Bbf
  actn_k<80, 80><<<16 * 6400 * 8 / 256, 256, 0, stream>>>(
      Bbf, st + 1 * 512, d1gw, d1gb);

  // stage 2: conv(Bbf)+PS -> Cbf (pre-norm), stats st2
  convm_k<80, 80, 16, 1, 10, 256, true, 2, 4>
    <<<dim3(40, 16 * 4), 256, 0, stream>>>((const uint4*)Bbf, wr2, d2b, Cbf,
                                           st + 2 * 512);
  // actn3: in-place GN+SiLU + enc1 (LDS-staged) on Cbf
  actne_k<<<16 * 100, 256, 0, stream>>>(Cbf, st + 2 * 512, d2gw, d2gb, enc1);

  // stage 3: conv(Cbf) -> Dbf (pre-norm), stats st3
  convm_k<160, 160, 16, 1, 10, 64, false, 2, 4>
    <<<dim3(160, 16), 256, 0, stream>>>((const uint4*)Cbf, wr3, d3b, Dbf,
                                        st + 3 * 512);

  // readout: Y = 1x1conv(GN_SiLU(Dbf))
  readout_k<<<16 * 25600 * 8 / 256, 256, 0, stream>>>(Dbf, st + 3 * 512,
      d3gw, d3gb, rw, rb, Y);

  feamap_k<<<(16 * 3 * 1600 + 255) / 256, 256, 0, stream>>>(Y, fw, argx);
  nz_k<<<(16 * 3 * 256 + 255) / 256, 256, 0, stream>>>(attn, nzv);
  final_k<<<(16 * 3 * 25600 + 255) / 256, 256, 0, stream>>>(Y, attn, nzv, argx,
      (float*)d_out);
}